// Round 9
// baseline (496.926 us; speedup 1.0000x reference)
//
#include <hip/hip_runtime.h>

typedef __attribute__((ext_vector_type(8))) short bf16x8;
typedef __attribute__((ext_vector_type(4))) float f32x4;

// ---- bf16 (as ushort) helpers ----
__device__ __forceinline__ float b2f(unsigned short u) {
    return __uint_as_float(((unsigned int)u) << 16);
}
__device__ __forceinline__ unsigned short f2b(float f) {
    unsigned int u = __float_as_uint(f);
    unsigned int r = (u + 0x7FFFu + ((u >> 16) & 1u)) >> 16;   // RNE
    return (unsigned short)r;
}

#define EDGE_CHUNK 2048

// ---------------------------------------------------------------------------
// prep_build (round 20): weight prep AND bucket-CSR build in ONE dispatch.
// Both phases are thin (<=32 VGPR, 0 LDS) so no round-6 occupancy trap.
// ---------------------------------------------------------------------------
__global__ __launch_bounds__(256) void prep_build_kernel(
    const float* __restrict__ W0r, const float* __restrict__ W0i, unsigned short* __restrict__ V0,
    const float* __restrict__ M0r, const float* __restrict__ M0i, unsigned short* __restrict__ VM0,
    const float* __restrict__ W1r, const float* __restrict__ W1i, unsigned short* __restrict__ V1,
    const float* __restrict__ M1r, const float* __restrict__ M1i, unsigned short* __restrict__ VM1,
    const int* __restrict__ src, const int* __restrict__ dst,
    int* __restrict__ deg, int* __restrict__ csr, int E, int N)
{
    int b = blockIdx.x;
    if (b < 64) {                       // V0 real
        int idx = b * 256 + threadIdx.x;
        int j = idx >> 7, k = idx & 127;
        V0[(size_t)(2 * j) * 128 + k]     = f2b(W0r[idx]);
        V0[(size_t)(2 * j + 1) * 128 + k] = f2b(W0i[idx]);
    } else if (b < 128) {               // VM0 cplx
        int idx = (b - 64) * 256 + threadIdx.x;
        int j = idx >> 7, kk = idx & 127;
        float wr = M0r[idx], wi = M0i[idx];
        unsigned short* r0 = VM0 + (size_t)(2 * j) * 256 + 2 * kk;
        unsigned short* r1 = VM0 + (size_t)(2 * j + 1) * 256 + 2 * kk;
        r0[0] = f2b(wr);  r0[1] = f2b(-wi);
        r1[0] = f2b(wi);  r1[1] = f2b(wr);
    } else if (b < 160) {               // V1 cplx
        int idx = (b - 128) * 256 + threadIdx.x;
        int j = idx >> 7, kk = idx & 127;
        float wr = W1r[idx], wi = W1i[idx];
        unsigned short* r0 = V1 + (size_t)(2 * j) * 256 + 2 * kk;
        unsigned short* r1 = V1 + (size_t)(2 * j + 1) * 256 + 2 * kk;
        r0[0] = f2b(wr);  r0[1] = f2b(-wi);
        r1[0] = f2b(wi);  r1[1] = f2b(wr);
    } else if (b < 176) {               // VM1 cplx
        int idx = (b - 160) * 256 + threadIdx.x;
        int j = idx >> 6, kk = idx & 63;
        float wr = M1r[idx], wi = M1i[idx];
        unsigned short* r0 = VM1 + (size_t)(2 * j) * 128 + 2 * kk;
        unsigned short* r1 = VM1 + (size_t)(2 * j + 1) * 128 + 2 * kk;
        r0[0] = f2b(wr);  r0[1] = f2b(-wi);
        r1[0] = f2b(wi);  r1[1] = f2b(wr);
    } else {                            // bucket-CSR build
        int vb = b - 176;
        int x  = vb & 7;
        int c  = vb >> 3;
        int lo = (int)((long long)N * x / 8);
        int hi = (int)((long long)N * (x + 1) / 8);
        int base = c * EDGE_CHUNK;
        int end  = min(base + EDGE_CHUNK, E);
        for (int e = base + threadIdx.x; e < end; e += 256) {
            int d = __builtin_nontemporal_load(dst + e);
            if (d >= lo && d < hi) {
                int s = __builtin_nontemporal_load(src + e);
                if ((unsigned)s < (unsigned)N) {
                    int pos = atomicAdd(&deg[d], 1);
                    if (pos < 64) csr[((size_t)d << 6) + pos] = s;
                }
            }
        }
    }
}

// ---------------------------------------------------------------------------
// MFMA complex GEMM as real GEMM (round 13 wave partition).
// AMODE: 0 = fp32 real input, 1 = bf16 cplx input, 2 = fp8 cplx input
// scaled by 1/64 (round 21 — expand multiplies by 64, exact pow2 shift).
// WF8 (round 14): non-MIX epilogue also emits fp8(e4m3) gather payload.
// ---------------------------------------------------------------------------
template<int Kr, int TWOJ, int AMODE, bool CRELU, bool MIX, bool WF8>
__global__ __launch_bounds__(256) void mfma_cgemm_kernel(
    const void* __restrict__ Xv,
    const unsigned short* __restrict__ Vg,
    const float* __restrict__ br, const float* __restrict__ bi,
    const float* __restrict__ trp, const float* __restrict__ tip,
    const unsigned short* __restrict__ Hin, const int* __restrict__ degp,
    unsigned short* __restrict__ Out, unsigned char* __restrict__ Of8,
    int nNodes)
{
    constexpr int TILES  = TWOJ / 16;
    constexpr int FT     = TILES / 4;   // feature tiles per wave
    constexpr int CHUNKS = Kr / 32;
    constexpr int VROW   = 40;          // 80B row stride (16B-aligned)
    static_assert(TILES % 4 == 0, "TILES % 4");

    __shared__ __align__(16) unsigned short sV[TWOJ * VROW];
    __shared__ __align__(16) unsigned short sA[64 * VROW];

    const int tid  = threadIdx.x;
    const int w    = tid >> 6;
    const int lane = tid & 63;
    const int l15  = lane & 15;
    const int q    = lane >> 4;
    const int n0   = blockIdx.x * 64;
    const int tq   = w * FT;            // this wave's first feature tile

    f32x4 acc[FT][4];
    #pragma unroll
    for (int t = 0; t < FT; ++t)
        #pragma unroll
        for (int nt = 0; nt < 4; ++nt) acc[t][nt] = (f32x4){0.f, 0.f, 0.f, 0.f};

    for (int kc = 0; kc < CHUNKS; ++kc) {
        // ---- stage V chunk ----
        #pragma unroll
        for (int it = 0; it < TWOJ / 64; ++it) {
            int idx = it * 256 + tid;
            int row = idx >> 2;
            int seg = idx & 3;
            *(uint4*)(sV + row * VROW + seg * 8) =
                *(const uint4*)(Vg + (size_t)row * Kr + kc * 32 + seg * 8);
        }
        // ---- stage A chunk ----
        if constexpr (AMODE == 0) {
            const float* X = (const float*)Xv;
            #pragma unroll
            for (int it = 0; it < 2; ++it) {
                int idx = it * 256 + tid;
                int nl = idx >> 3;
                int cg = idx & 7;
                int n  = n0 + nl;
                f32x4 v = (f32x4){0.f, 0.f, 0.f, 0.f};
                if (n < nNodes)
                    v = __builtin_nontemporal_load(
                        (const f32x4*)(X + (size_t)n * Kr + kc * 32 + cg * 4));
                *(ushort4*)(sA + nl * VROW + cg * 4) =
                    make_ushort4(f2b(v[0]), f2b(v[1]), f2b(v[2]), f2b(v[3]));
            }
        } else if constexpr (AMODE == 1) {
            const unsigned short* X = (const unsigned short*)Xv;
            int nl  = tid >> 2;
            int seg = tid & 3;
            int n   = n0 + nl;
            uint4 v = make_uint4(0, 0, 0, 0);
            if (n < nNodes)
                v = *(const uint4*)(X + (size_t)n * Kr + kc * 32 + seg * 8);
            *(uint4*)(sA + nl * VROW + seg * 8) = v;
        } else {
            // fp8 input scaled by 1/64: expand and multiply back by 64 (exact)
            const unsigned char* X = (const unsigned char*)Xv;
            constexpr float US = 64.0f;
            int nl  = tid >> 2;
            int seg = tid & 3;
            int n   = n0 + nl;
            uint2 v = make_uint2(0, 0);
            if (n < nNodes)
                v = *(const uint2*)(X + (size_t)n * Kr + kc * 32 + seg * 8);
            auto p0 = __builtin_amdgcn_cvt_pk_f32_fp8(v.x, false);
            auto p1 = __builtin_amdgcn_cvt_pk_f32_fp8(v.x, true);
            auto p2 = __builtin_amdgcn_cvt_pk_f32_fp8(v.y, false);
            auto p3 = __builtin_amdgcn_cvt_pk_f32_fp8(v.y, true);
            *(ushort4*)(sA + nl * VROW + seg * 8) =
                make_ushort4(f2b(p0[0] * US), f2b(p0[1] * US),
                             f2b(p1[0] * US), f2b(p1[1] * US));
            *(ushort4*)(sA + nl * VROW + seg * 8 + 4) =
                make_ushort4(f2b(p2[0] * US), f2b(p2[1] * US),
                             f2b(p3[0] * US), f2b(p3[1] * US));
        }
        __syncthreads();

        // ---- inner: 4 bfrags reused across FT afrags ----
        bf16x8 bfrag[4];
        #pragma unroll
        for (int nt = 0; nt < 4; ++nt)
            bfrag[nt] = *(const bf16x8*)(sA + (nt * 16 + l15) * VROW + q * 8);
        #pragma unroll
        for (int t = 0; t < FT; ++t) {
            bf16x8 afrag = *(const bf16x8*)(sV + ((tq + t) * 16 + l15) * VROW + q * 8);
            #pragma unroll
            for (int nt = 0; nt < 4; ++nt)
                acc[t][nt] = __builtin_amdgcn_mfma_f32_16x16x32_bf16(
                    afrag, bfrag[nt], acc[t][nt], 0, 0, 0);
        }
        __syncthreads();
    }

    // ---- epilogue ----
    float Fr = 1.f, Fi = 0.f, efr = 1.f, efi = 0.f;
    if constexpr (MIX) {
        float tr = trp[0], ti = tip[0];
        float er  = expf(ti);
        float tfr =  er * cosf(tr);
        float tfi = -er * sinf(tr);
        float eh  = expf(0.5f * ti);
        efr =  eh * cosf(0.5f * tr);
        efi = -eh * sinf(0.5f * tr);
        float omr = 1.f - efr, omi = -efi;
        Fr = tfr * omr - tfi * omi;
        Fi = tfr * omi + tfi * omr;
    }
    #pragma unroll
    for (int nt = 0; nt < 4; ++nt) {
        int n = n0 + nt * 16 + l15;
        if (n >= nNodes) continue;
        float dg = 0.f;
        if constexpr (MIX) dg = (float)degp[n];
        #pragma unroll
        for (int t = 0; t < FT; ++t) {
            int f0 = (tq + t) * 16 + q * 4;
            int j0 = f0 >> 1;
            float re0, im0, re1, im1;
            if constexpr (MIX) {
                float ar0 = acc[t][nt][0] + dg * br[j0];
                float ai0 = acc[t][nt][1] + dg * bi[j0];
                float ar1 = acc[t][nt][2] + dg * br[j0 + 1];
                float ai1 = acc[t][nt][3] + dg * bi[j0 + 1];
                re0 = ar0 * Fr - ai0 * Fi;  im0 = ar0 * Fi + ai0 * Fr;
                re1 = ar1 * Fr - ai1 * Fi;  im1 = ar1 * Fi + ai1 * Fr;
                ushort4 hu = *(const ushort4*)(Hin + (size_t)n * TWOJ + f0);
                float hr0 = b2f(hu.x), hi0 = b2f(hu.y), hr1 = b2f(hu.z), hi1 = b2f(hu.w);
                re0 += hr0 * efr - hi0 * efi;  im0 += hr0 * efi + hi0 * efr;
                re1 += hr1 * efr - hi1 * efi;  im1 += hr1 * efi + hi1 * efr;
            } else {
                re0 = acc[t][nt][0] + br[j0];
                im0 = acc[t][nt][1] + bi[j0];
                re1 = acc[t][nt][2] + br[j0 + 1];
                im1 = acc[t][nt][3] + bi[j0 + 1];
                if constexpr (CRELU) {
                    re0 = fmaxf(re0, 0.f); im0 = fmaxf(im0, 0.f);
                    re1 = fmaxf(re1, 0.f); im1 = fmaxf(im1, 0.f);
                }
            }
            *(ushort4*)(Out + (size_t)n * TWOJ + f0) =
                make_ushort4(f2b(re0), f2b(im0), f2b(re1), f2b(im1));
            if constexpr (WF8) {
                int pk = 0;
                pk = __builtin_amdgcn_cvt_pk_fp8_f32(re0, im0, pk, false);
                pk = __builtin_amdgcn_cvt_pk_fp8_f32(re1, im1, pk, true);
                *(int*)(Of8 + (size_t)n * TWOJ + f0) = pk;
            }
        }
    }
}

// ---------------------------------------------------------------------------
// Gather-sum, fp8 payload IN and OUT (round 21: output scaled by 1/64 so
// sums never exceed e4m3 range — unscaled overflow produced NaN in round 8).
// ---------------------------------------------------------------------------
template<int ROWE>
__global__ __launch_bounds__(256) void gather_f8_kernel(
    const unsigned char* __restrict__ h8, unsigned char* __restrict__ agg8,
    const int* __restrict__ deg, const int* __restrict__ csr, int N)
{
    constexpr int LPR = ROWE / 16;   // lanes per node: 16 or 8
    constexpr int NPW = 64 / LPR;    // nodes per wave: 4 or 8
    const int tid  = threadIdx.x;
    const int lane = tid & 63;
    const int wid  = (blockIdx.x * 256 + tid) >> 6;
    if (wid * NPW >= N) return;
    const int g    = lane / LPR;
    const int sub  = lane % LPR;
    const int nid  = wid * NPW + g;
    const bool nv  = nid < N;
    int dg = 0;
    if (nv) dg = min(deg[nid], 64);

    // ---- whole csr row (64 ints) into registers across the group ----
    uint4 cq0 = make_uint4(0, 0, 0, 0), cq1 = make_uint4(0, 0, 0, 0);
    if (nv) {
        const uint4* cp = (const uint4*)csr + ((size_t)nid << 4);
        cq0 = cp[sub];                       // entries 4*sub .. 4*sub+3
        if constexpr (LPR == 8) cq1 = cp[8 + sub];   // entries 32+4*sub ..
    }

    // ---- wave-max degree (dg uniform within each group) ----
    int mx = dg;
    mx = max(mx, __shfl_xor(mx, 32, 64));
    mx = max(mx, __shfl_xor(mx, 16, 64));
    if constexpr (LPR == 8) mx = max(mx, __shfl_xor(mx, 8, 64));

    float a[16];
    #pragma unroll
    for (int k = 0; k < 16; ++k) a[k] = 0.f;

    const unsigned char* hp = h8 + sub * 16;
    const int gb = g * LPR;

    #define CVT16(uu)                                                          \
        {                                                                      \
            auto p0 = __builtin_amdgcn_cvt_pk_f32_fp8((uu).x, false);          \
            a[0] += p0[0];   a[1] += p0[1];                                    \
            auto p1 = __builtin_amdgcn_cvt_pk_f32_fp8((uu).x, true);           \
            a[2] += p1[0];   a[3] += p1[1];                                    \
            auto p2 = __builtin_amdgcn_cvt_pk_f32_fp8((uu).y, false);          \
            a[4] += p2[0];   a[5] += p2[1];                                    \
            auto p3 = __builtin_amdgcn_cvt_pk_f32_fp8((uu).y, true);           \
            a[6] += p3[0];   a[7] += p3[1];                                    \
            auto p4 = __builtin_amdgcn_cvt_pk_f32_fp8((uu).z, false);          \
            a[8] += p4[0];   a[9] += p4[1];                                    \
            auto p5 = __builtin_amdgcn_cvt_pk_f32_fp8((uu).z, true);           \
            a[10] += p5[0];  a[11] += p5[1];                                   \
            auto p6 = __builtin_amdgcn_cvt_pk_f32_fp8((uu).w, false);          \
            a[12] += p6[0];  a[13] += p6[1];                                   \
            auto p7 = __builtin_amdgcn_cvt_pk_f32_fp8((uu).w, true);           \
            a[14] += p7[0];  a[15] += p7[1];                                   \
        }

    for (int e = 0; e < mx; e += 8) {
        uint4 cq = cq0;
        if constexpr (LPR == 8) { if (e & 32) cq = cq1; }
        const int o0 = gb + ((e & (4 * LPR - 1)) >> 2);
        const int o1 = o0 + 1;
        int s0 = __shfl((int)cq.x, o0, 64);
        int s1 = __shfl((int)cq.y, o0, 64);
        int s2 = __shfl((int)cq.z, o0, 64);
        int s3 = __shfl((int)cq.w, o0, 64);
        int s4 = __shfl((int)cq.x, o1, 64);
        int s5 = __shfl((int)cq.y, o1, 64);
        int s6 = __shfl((int)cq.z, o1, 64);
        int s7 = __shfl((int)cq.w, o1, 64);
        uint4 u0 = make_uint4(0,0,0,0), u1 = make_uint4(0,0,0,0);
        uint4 u2 = make_uint4(0,0,0,0), u3 = make_uint4(0,0,0,0);
        uint4 u4 = make_uint4(0,0,0,0), u5 = make_uint4(0,0,0,0);
        uint4 u6 = make_uint4(0,0,0,0), u7 = make_uint4(0,0,0,0);
        if (e + 0 < dg) u0 = *(const uint4*)(hp + (size_t)(unsigned)s0 * ROWE);
        if (e + 1 < dg) u1 = *(const uint4*)(hp + (size_t)(unsigned)s1 * ROWE);
        if (e + 2 < dg) u2 = *(const uint4*)(hp + (size_t)(unsigned)s2 * ROWE);
        if (e + 3 < dg) u3 = *(const uint4*)(hp + (size_t)(unsigned)s3 * ROWE);
        if (e + 4 < dg) u4 = *(const uint4*)(hp + (size_t)(unsigned)s4 * ROWE);
        if (e + 5 < dg) u5 = *(const uint4*)(hp + (size_t)(unsigned)s5 * ROWE);
        if (e + 6 < dg) u6 = *(const uint4*)(hp + (size_t)(unsigned)s6 * ROWE);
        if (e + 7 < dg) u7 = *(const uint4*)(hp + (size_t)(unsigned)s7 * ROWE);
        CVT16(u0) CVT16(u1) CVT16(u2) CVT16(u3)
        CVT16(u4) CVT16(u5) CVT16(u6) CVT16(u7)
    }
    #undef CVT16

    if (nv) {
        // scale sums by 1/64 (exact pow2) so fp8 pack cannot overflow;
        // GEMM A-staging multiplies back by 64.
        constexpr float SCL = 1.0f / 64.0f;
        int k0 = 0, k1 = 0, k2 = 0, k3 = 0;
        k0 = __builtin_amdgcn_cvt_pk_fp8_f32(a[0]  * SCL, a[1]  * SCL, k0, false);
        k0 = __builtin_amdgcn_cvt_pk_fp8_f32(a[2]  * SCL, a[3]  * SCL, k0, true);
        k1 = __builtin_amdgcn_cvt_pk_fp8_f32(a[4]  * SCL, a[5]  * SCL, k1, false);
        k1 = __builtin_amdgcn_cvt_pk_fp8_f32(a[6]  * SCL, a[7]  * SCL, k1, true);
        k2 = __builtin_amdgcn_cvt_pk_fp8_f32(a[8]  * SCL, a[9]  * SCL, k2, false);
        k2 = __builtin_amdgcn_cvt_pk_fp8_f32(a[10] * SCL, a[11] * SCL, k2, true);
        k3 = __builtin_amdgcn_cvt_pk_fp8_f32(a[12] * SCL, a[13] * SCL, k3, false);
        k3 = __builtin_amdgcn_cvt_pk_fp8_f32(a[14] * SCL, a[15] * SCL, k3, true);
        *(uint4*)(agg8 + (size_t)nid * ROWE + sub * 16) =
            make_uint4((unsigned)k0, (unsigned)k1, (unsigned)k2, (unsigned)k3);
    }
}

// ---------------------------------------------------------------------------
// abs + per-graph sum over final z [N,64]c bf16 (row = 128 ushorts).
// ---------------------------------------------------------------------------
__global__ __launch_bounds__(256) void abs_reduce_kernel(
    const unsigned short* __restrict__ z, const int* __restrict__ batch,
    float* __restrict__ sums, int N)
{
    constexpr int NPW = 16;
    int wid  = (blockIdx.x * 256 + threadIdx.x) >> 6;
    int lane = threadIdx.x & 63;
    int nBeg = wid * NPW;
    if (nBeg >= N) return;
    int nEnd = min(nBeg + NPW, N);

    float acc = 0.f;
    int cur_g = batch[nBeg];
    for (int n = nBeg; n < nEnd; ++n) {
        unsigned int u = *(const unsigned int*)(z + ((size_t)n << 7) + (lane << 1));
        float zr = b2f((unsigned short)(u & 0xffffu));
        float zi = b2f((unsigned short)(u >> 16));
        float a = sqrtf(zr * zr + zi * zi);
        int g = batch[n];
        if (g != cur_g) {
            if ((unsigned)cur_g < 64u) unsafeAtomicAdd(&sums[cur_g * 64 + lane], acc);
            acc = 0.f;
            cur_g = g;
        }
        acc += a;
    }
    if ((unsigned)cur_g < 64u) unsafeAtomicAdd(&sums[cur_g * 64 + lane], acc);
}

// per-graph count via binary search (batch sorted) + mean + log_softmax
__global__ __launch_bounds__(64) void finalize_kernel(
    const float* __restrict__ sums, const int* __restrict__ batch,
    float* __restrict__ out, int N)
{
    int g = blockIdx.x, d = threadIdx.x;
    __shared__ int cnt_s;
    if (d == 0) {
        int lo = 0, hi = N;
        while (lo < hi) { int mid = (lo + hi) >> 1; if (batch[mid] < g) lo = mid + 1; else hi = mid; }
        int lo2 = lo, hi2 = N;
        while (lo2 < hi2) { int mid = (lo2 + hi2) >> 1; if (batch[mid] < g + 1) lo2 = mid + 1; else hi2 = mid; }
        cnt_s = lo2 - lo;
    }
    __syncthreads();
    float c = fmaxf((float)cnt_s, 1.0f);
    float m = sums[g * 64 + d] / c;
    float mx = m;
    #pragma unroll
    for (int o = 32; o > 0; o >>= 1) mx = fmaxf(mx, __shfl_xor(mx, o, 64));
    float e = expf(m - mx);
    float s = e;
    #pragma unroll
    for (int o = 32; o > 0; o >>= 1) s += __shfl_xor(s, o, 64);
    out[g * 64 + d] = m - mx - logf(s);
}

extern "C" void kernel_launch(void* const* d_in, const int* in_sizes, int n_in,
                              void* d_out, int out_size, void* d_ws, size_t ws_size,
                              hipStream_t stream)
{
    const float* x   = (const float*)d_in[0];
    const float* W0r = (const float*)d_in[1];
    const float* W0i = (const float*)d_in[2];
    const float* b0r = (const float*)d_in[3];
    const float* b0i = (const float*)d_in[4];
    const float* M0r = (const float*)d_in[5];
    const float* M0i = (const float*)d_in[6];
    const float* c0r = (const float*)d_in[7];
    const float* c0i = (const float*)d_in[8];
    const float* t0r = (const float*)d_in[9];
    const float* t0i = (const float*)d_in[10];
    const float* W1r = (const float*)d_in[11];
    const float* W1i = (const float*)d_in[12];
    const float* b1r = (const float*)d_in[13];
    const float* b1i = (const float*)d_in[14];
    const float* M1r = (const float*)d_in[15];
    const float* M1i = (const float*)d_in[16];
    const float* c1r = (const float*)d_in[17];
    const float* c1i = (const float*)d_in[18];
    const float* t1r = (const float*)d_in[19];
    const float* t1i = (const float*)d_in[20];
    const int* edge  = (const int*)d_in[21];
    const int* batch = (const int*)d_in[22];

    const int N = in_sizes[0] / 128;
    const int E = in_sizes[21] / 2;
    const int* src = edge;
    const int* dst = edge + E;

    // ---- workspace (~206 MB) ----
    unsigned short* h0   = (unsigned short*)d_ws;       // becomes x1, in place
    unsigned short* aggA = h0 + (size_t)N * 256;        // region reused as fp8
    unsigned short* h1   = aggA + (size_t)N * 256;      // becomes z, in place
    unsigned short* aggB = h1 + (size_t)N * 128;        // region reused as fp8
    int*   deg  = (int*)(aggB + (size_t)N * 128);
    int*   csr  = deg + N;
    float* sums = (float*)(csr + (size_t)N * 64);
    unsigned short* V0  = (unsigned short*)(sums + 4096);  // [256,128]
    unsigned short* VM0 = V0  + 256 * 128;                 // [256,256]
    unsigned short* V1  = VM0 + 256 * 256;                 // [128,256]
    unsigned short* VM1 = V1  + 128 * 256;                 // [128,128]
    // fp8 gather payload; h0f8 (N*256B) and h1f8 (N*128B) share one region.
    unsigned char* hf8 = (unsigned char*)(VM1 + 128 * 128);
    unsigned char* aggA8 = (unsigned char*)aggA;   // N*256 B
    unsigned char* aggB8 = (unsigned char*)aggB;   // N*128 B

    const int gemmGrid  = (N + 63) / 64;
    const int buildGrid = ((E + EDGE_CHUNK - 1) / EDGE_CHUNK) * 8;
    const int pbGrid    = 176 + buildGrid;
    const int g256Grid  = (N + 15) / 16;   // 4 nodes/wave, 4 waves/block
    const int g128Grid  = (N + 31) / 32;   // 8 nodes/wave, 4 waves/block
    const int wave16Grid = ((N + 15) / 16 * 64 + 255) / 256;

    // ---- zero deg/sums (DMA, stream-ordered), then fused prep+build ----
    hipMemsetAsync(deg, 0, N * sizeof(int), stream);
    hipMemsetAsync(sums, 0, 4096 * sizeof(float), stream);
    prep_build_kernel<<<pbGrid, 256, 0, stream>>>(
        W0r, W0i, V0, M0r, M0i, VM0, W1r, W1i, V1, M1r, M1i, VM1,
        src, dst, deg, csr, E, N);

    // ---- layer 0 ----
    mfma_cgemm_kernel<128,256,0,true,false,true><<<gemmGrid, 256, 0, stream>>>(
        x, V0, b0r, b0i, nullptr, nullptr, nullptr, nullptr, h0, hf8, N);
    gather_f8_kernel<256><<<g256Grid, 256, 0, stream>>>(hf8, aggA8, deg, csr, N);
    mfma_cgemm_kernel<256,256,2,false,true,false><<<gemmGrid, 256, 0, stream>>>(
        aggA8, VM0, c0r, c0i, t0r, t0i, h0, deg, h0, nullptr, N);

    // ---- layer 1 ----
    mfma_cgemm_kernel<256,128,1,true,false,true><<<gemmGrid, 256, 0, stream>>>(
        h0, V1, b1r, b1i, nullptr, nullptr, nullptr, nullptr, h1, hf8, N);
    gather_f8_kernel<128><<<g128Grid, 256, 0, stream>>>(hf8, aggB8, deg, csr, N);
    mfma_cgemm_kernel<128,128,2,false,true,false><<<gemmGrid, 256, 0, stream>>>(
        aggB8, VM1, c1r, c1i, t1r, t1i, h1, deg, h1, nullptr, N);

    // ---- readout ----
    abs_reduce_kernel<<<wave16Grid, 256, 0, stream>>>(h1, batch, sums, N);
    finalize_kernel<<<64, 64, 0, stream>>>(sums, batch, (float*)d_out, N);
}

// Round 11
// 492.522 us; speedup vs baseline: 1.0089x; 1.0089x over previous
//
#include <hip/hip_runtime.h>

typedef __attribute__((ext_vector_type(8))) short bf16x8;
typedef __attribute__((ext_vector_type(4))) float f32x4;

// ---- bf16 (as ushort) helpers ----
__device__ __forceinline__ float b2f(unsigned short u) {
    return __uint_as_float(((unsigned int)u) << 16);
}
__device__ __forceinline__ unsigned short f2b(float f) {
    unsigned int u = __float_as_uint(f);
    unsigned int r = (u + 0x7FFFu + ((u >> 16) & 1u)) >> 16;   // RNE
    return (unsigned short)r;
}

#define EDGE_CHUNK 2048

// ---------------------------------------------------------------------------
// prep_build (round 20 — proven r9: prep fully hidden under build, 84 us).
// Weight prep AND bucket-CSR build in ONE dispatch; both phases thin
// (<=32 VGPR, 0 LDS) so no round-6 occupancy trap.
// ---------------------------------------------------------------------------
__global__ __launch_bounds__(256) void prep_build_kernel(
    const float* __restrict__ W0r, const float* __restrict__ W0i, unsigned short* __restrict__ V0,
    const float* __restrict__ M0r, const float* __restrict__ M0i, unsigned short* __restrict__ VM0,
    const float* __restrict__ W1r, const float* __restrict__ W1i, unsigned short* __restrict__ V1,
    const float* __restrict__ M1r, const float* __restrict__ M1i, unsigned short* __restrict__ VM1,
    const int* __restrict__ src, const int* __restrict__ dst,
    int* __restrict__ deg, int* __restrict__ csr, int E, int N)
{
    int b = blockIdx.x;
    if (b < 64) {                       // V0 real
        int idx = b * 256 + threadIdx.x;
        int j = idx >> 7, k = idx & 127;
        V0[(size_t)(2 * j) * 128 + k]     = f2b(W0r[idx]);
        V0[(size_t)(2 * j + 1) * 128 + k] = f2b(W0i[idx]);
    } else if (b < 128) {               // VM0 cplx
        int idx = (b - 64) * 256 + threadIdx.x;
        int j = idx >> 7, kk = idx & 127;
        float wr = M0r[idx], wi = M0i[idx];
        unsigned short* r0 = VM0 + (size_t)(2 * j) * 256 + 2 * kk;
        unsigned short* r1 = VM0 + (size_t)(2 * j + 1) * 256 + 2 * kk;
        r0[0] = f2b(wr);  r0[1] = f2b(-wi);
        r1[0] = f2b(wi);  r1[1] = f2b(wr);
    } else if (b < 160) {               // V1 cplx
        int idx = (b - 128) * 256 + threadIdx.x;
        int j = idx >> 7, kk = idx & 127;
        float wr = W1r[idx], wi = W1i[idx];
        unsigned short* r0 = V1 + (size_t)(2 * j) * 256 + 2 * kk;
        unsigned short* r1 = V1 + (size_t)(2 * j + 1) * 256 + 2 * kk;
        r0[0] = f2b(wr);  r0[1] = f2b(-wi);
        r1[0] = f2b(wi);  r1[1] = f2b(wr);
    } else if (b < 176) {               // VM1 cplx
        int idx = (b - 160) * 256 + threadIdx.x;
        int j = idx >> 6, kk = idx & 63;
        float wr = M1r[idx], wi = M1i[idx];
        unsigned short* r0 = VM1 + (size_t)(2 * j) * 128 + 2 * kk;
        unsigned short* r1 = VM1 + (size_t)(2 * j + 1) * 128 + 2 * kk;
        r0[0] = f2b(wr);  r0[1] = f2b(-wi);
        r1[0] = f2b(wi);  r1[1] = f2b(wr);
    } else {                            // bucket-CSR build
        int vb = b - 176;
        int x  = vb & 7;
        int c  = vb >> 3;
        int lo = (int)((long long)N * x / 8);
        int hi = (int)((long long)N * (x + 1) / 8);
        int base = c * EDGE_CHUNK;
        int end  = min(base + EDGE_CHUNK, E);
        for (int e = base + threadIdx.x; e < end; e += 256) {
            int d = __builtin_nontemporal_load(dst + e);
            if (d >= lo && d < hi) {
                int s = __builtin_nontemporal_load(src + e);
                if ((unsigned)s < (unsigned)N) {
                    int pos = atomicAdd(&deg[d], 1);
                    if (pos < 64) csr[((size_t)d << 6) + pos] = s;
                }
            }
        }
    }
}

// ---------------------------------------------------------------------------
// MFMA complex GEMM as real GEMM (round 13 wave partition).
// AMODE: 0 = fp32 real input, 1 = bf16 cplx input.
// Round-10 A/B: fp8 agg interface (r9, 497 us) vs bf16 agg (this, vs r7 488).
// WF8 (round 14): non-MIX epilogue also emits fp8(e4m3) gather payload.
// ---------------------------------------------------------------------------
template<int Kr, int TWOJ, int AMODE, bool CRELU, bool MIX, bool WF8>
__global__ __launch_bounds__(256) void mfma_cgemm_kernel(
    const void* __restrict__ Xv,
    const unsigned short* __restrict__ Vg,
    const float* __restrict__ br, const float* __restrict__ bi,
    const float* __restrict__ trp, const float* __restrict__ tip,
    const unsigned short* __restrict__ Hin, const int* __restrict__ degp,
    unsigned short* __restrict__ Out, unsigned char* __restrict__ Of8,
    int nNodes)
{
    constexpr int TILES  = TWOJ / 16;
    constexpr int FT     = TILES / 4;   // feature tiles per wave
    constexpr int CHUNKS = Kr / 32;
    constexpr int VROW   = 40;          // 80B row stride (16B-aligned)
    static_assert(TILES % 4 == 0, "TILES % 4");

    __shared__ __align__(16) unsigned short sV[TWOJ * VROW];
    __shared__ __align__(16) unsigned short sA[64 * VROW];

    const int tid  = threadIdx.x;
    const int w    = tid >> 6;
    const int lane = tid & 63;
    const int l15  = lane & 15;
    const int q    = lane >> 4;
    const int n0   = blockIdx.x * 64;
    const int tq   = w * FT;            // this wave's first feature tile

    f32x4 acc[FT][4];
    #pragma unroll
    for (int t = 0; t < FT; ++t)
        #pragma unroll
        for (int nt = 0; nt < 4; ++nt) acc[t][nt] = (f32x4){0.f, 0.f, 0.f, 0.f};

    for (int kc = 0; kc < CHUNKS; ++kc) {
        // ---- stage V chunk ----
        #pragma unroll
        for (int it = 0; it < TWOJ / 64; ++it) {
            int idx = it * 256 + tid;
            int row = idx >> 2;
            int seg = idx & 3;
            *(uint4*)(sV + row * VROW + seg * 8) =
                *(const uint4*)(Vg + (size_t)row * Kr + kc * 32 + seg * 8);
        }
        // ---- stage A chunk ----
        if constexpr (AMODE == 0) {
            const float* X = (const float*)Xv;
            #pragma unroll
            for (int it = 0; it < 2; ++it) {
                int idx = it * 256 + tid;
                int nl = idx >> 3;
                int cg = idx & 7;
                int n  = n0 + nl;
                f32x4 v = (f32x4){0.f, 0.f, 0.f, 0.f};
                if (n < nNodes)
                    v = __builtin_nontemporal_load(
                        (const f32x4*)(X + (size_t)n * Kr + kc * 32 + cg * 4));
                *(ushort4*)(sA + nl * VROW + cg * 4) =
                    make_ushort4(f2b(v[0]), f2b(v[1]), f2b(v[2]), f2b(v[3]));
            }
        } else {
            const unsigned short* X = (const unsigned short*)Xv;
            int nl  = tid >> 2;
            int seg = tid & 3;
            int n   = n0 + nl;
            uint4 v = make_uint4(0, 0, 0, 0);
            if (n < nNodes)
                v = *(const uint4*)(X + (size_t)n * Kr + kc * 32 + seg * 8);
            *(uint4*)(sA + nl * VROW + seg * 8) = v;
        }
        __syncthreads();

        // ---- inner: 4 bfrags reused across FT afrags ----
        bf16x8 bfrag[4];
        #pragma unroll
        for (int nt = 0; nt < 4; ++nt)
            bfrag[nt] = *(const bf16x8*)(sA + (nt * 16 + l15) * VROW + q * 8);
        #pragma unroll
        for (int t = 0; t < FT; ++t) {
            bf16x8 afrag = *(const bf16x8*)(sV + ((tq + t) * 16 + l15) * VROW + q * 8);
            #pragma unroll
            for (int nt = 0; nt < 4; ++nt)
                acc[t][nt] = __builtin_amdgcn_mfma_f32_16x16x32_bf16(
                    afrag, bfrag[nt], acc[t][nt], 0, 0, 0);
        }
        __syncthreads();
    }

    // ---- epilogue ----
    float Fr = 1.f, Fi = 0.f, efr = 1.f, efi = 0.f;
    if constexpr (MIX) {
        float tr = trp[0], ti = tip[0];
        float er  = expf(ti);
        float tfr =  er * cosf(tr);
        float tfi = -er * sinf(tr);
        float eh  = expf(0.5f * ti);
        efr =  eh * cosf(0.5f * tr);
        efi = -eh * sinf(0.5f * tr);
        float omr = 1.f - efr, omi = -efi;
        Fr = tfr * omr - tfi * omi;
        Fi = tfr * omi + tfi * omr;
    }
    #pragma unroll
    for (int nt = 0; nt < 4; ++nt) {
        int n = n0 + nt * 16 + l15;
        if (n >= nNodes) continue;
        float dg = 0.f;
        if constexpr (MIX) dg = (float)degp[n];
        #pragma unroll
        for (int t = 0; t < FT; ++t) {
            int f0 = (tq + t) * 16 + q * 4;
            int j0 = f0 >> 1;
            float re0, im0, re1, im1;
            if constexpr (MIX) {
                float ar0 = acc[t][nt][0] + dg * br[j0];
                float ai0 = acc[t][nt][1] + dg * bi[j0];
                float ar1 = acc[t][nt][2] + dg * br[j0 + 1];
                float ai1 = acc[t][nt][3] + dg * bi[j0 + 1];
                re0 = ar0 * Fr - ai0 * Fi;  im0 = ar0 * Fi + ai0 * Fr;
                re1 = ar1 * Fr - ai1 * Fi;  im1 = ar1 * Fi + ai1 * Fr;
                ushort4 hu = *(const ushort4*)(Hin + (size_t)n * TWOJ + f0);
                float hr0 = b2f(hu.x), hi0 = b2f(hu.y), hr1 = b2f(hu.z), hi1 = b2f(hu.w);
                re0 += hr0 * efr - hi0 * efi;  im0 += hr0 * efi + hi0 * efr;
                re1 += hr1 * efr - hi1 * efi;  im1 += hr1 * efi + hi1 * efr;
            } else {
                re0 = acc[t][nt][0] + br[j0];
                im0 = acc[t][nt][1] + bi[j0];
                re1 = acc[t][nt][2] + br[j0 + 1];
                im1 = acc[t][nt][3] + bi[j0 + 1];
                if constexpr (CRELU) {
                    re0 = fmaxf(re0, 0.f); im0 = fmaxf(im0, 0.f);
                    re1 = fmaxf(re1, 0.f); im1 = fmaxf(im1, 0.f);
                }
            }
            *(ushort4*)(Out + (size_t)n * TWOJ + f0) =
                make_ushort4(f2b(re0), f2b(im0), f2b(re1), f2b(im1));
            if constexpr (WF8) {
                int pk = 0;
                pk = __builtin_amdgcn_cvt_pk_fp8_f32(re0, im0, pk, false);
                pk = __builtin_amdgcn_cvt_pk_fp8_f32(re1, im1, pk, true);
                *(int*)(Of8 + (size_t)n * TWOJ + f0) = pk;
            }
        }
    }
}

// ---------------------------------------------------------------------------
// Gather-sum, fp8 payload IN, bf16 agg OUT (round-7 proven interface).
// Node-per-lane-group (round 15).
// ---------------------------------------------------------------------------
template<int ROWE>
__global__ __launch_bounds__(256) void gather_f8_kernel(
    const unsigned char* __restrict__ h8, unsigned short* __restrict__ agg,
    const int* __restrict__ deg, const int* __restrict__ csr, int N)
{
    constexpr int LPR = ROWE / 16;   // lanes per node: 16 or 8
    constexpr int NPW = 64 / LPR;    // nodes per wave: 4 or 8
    const int tid  = threadIdx.x;
    const int lane = tid & 63;
    const int wid  = (blockIdx.x * 256 + tid) >> 6;
    if (wid * NPW >= N) return;
    const int g    = lane / LPR;
    const int sub  = lane % LPR;
    const int nid  = wid * NPW + g;
    const bool nv  = nid < N;
    int dg = 0;
    if (nv) dg = min(deg[nid], 64);

    // ---- whole csr row (64 ints) into registers across the group ----
    uint4 cq0 = make_uint4(0, 0, 0, 0), cq1 = make_uint4(0, 0, 0, 0);
    if (nv) {
        const uint4* cp = (const uint4*)csr + ((size_t)nid << 4);
        cq0 = cp[sub];                       // entries 4*sub .. 4*sub+3
        if constexpr (LPR == 8) cq1 = cp[8 + sub];   // entries 32+4*sub ..
    }

    // ---- wave-max degree (dg uniform within each group) ----
    int mx = dg;
    mx = max(mx, __shfl_xor(mx, 32, 64));
    mx = max(mx, __shfl_xor(mx, 16, 64));
    if constexpr (LPR == 8) mx = max(mx, __shfl_xor(mx, 8, 64));

    float a[16];
    #pragma unroll
    for (int k = 0; k < 16; ++k) a[k] = 0.f;

    const unsigned char* hp = h8 + sub * 16;
    const int gb = g * LPR;

    #define CVT16(uu)                                                          \
        {                                                                      \
            auto p0 = __builtin_amdgcn_cvt_pk_f32_fp8((uu).x, false);          \
            a[0] += p0[0];   a[1] += p0[1];                                    \
            auto p1 = __builtin_amdgcn_cvt_pk_f32_fp8((uu).x, true);           \
            a[2] += p1[0];   a[3] += p1[1];                                    \
            auto p2 = __builtin_amdgcn_cvt_pk_f32_fp8((uu).y, false);          \
            a[4] += p2[0];   a[5] += p2[1];                                    \
            auto p3 = __builtin_amdgcn_cvt_pk_f32_fp8((uu).y, true);           \
            a[6] += p3[0];   a[7] += p3[1];                                    \
            auto p4 = __builtin_amdgcn_cvt_pk_f32_fp8((uu).z, false);          \
            a[8] += p4[0];   a[9] += p4[1];                                    \
            auto p5 = __builtin_amdgcn_cvt_pk_f32_fp8((uu).z, true);           \
            a[10] += p5[0];  a[11] += p5[1];                                   \
            auto p6 = __builtin_amdgcn_cvt_pk_f32_fp8((uu).w, false);          \
            a[12] += p6[0];  a[13] += p6[1];                                   \
            auto p7 = __builtin_amdgcn_cvt_pk_f32_fp8((uu).w, true);           \
            a[14] += p7[0];  a[15] += p7[1];                                   \
        }

    for (int e = 0; e < mx; e += 8) {
        uint4 cq = cq0;
        if constexpr (LPR == 8) { if (e & 32) cq = cq1; }
        const int o0 = gb + ((e & (4 * LPR - 1)) >> 2);
        const int o1 = o0 + 1;
        int s0 = __shfl((int)cq.x, o0, 64);
        int s1 = __shfl((int)cq.y, o0, 64);
        int s2 = __shfl((int)cq.z, o0, 64);
        int s3 = __shfl((int)cq.w, o0, 64);
        int s4 = __shfl((int)cq.x, o1, 64);
        int s5 = __shfl((int)cq.y, o1, 64);
        int s6 = __shfl((int)cq.z, o1, 64);
        int s7 = __shfl((int)cq.w, o1, 64);
        uint4 u0 = make_uint4(0,0,0,0), u1 = make_uint4(0,0,0,0);
        uint4 u2 = make_uint4(0,0,0,0), u3 = make_uint4(0,0,0,0);
        uint4 u4 = make_uint4(0,0,0,0), u5 = make_uint4(0,0,0,0);
        uint4 u6 = make_uint4(0,0,0,0), u7 = make_uint4(0,0,0,0);
        if (e + 0 < dg) u0 = *(const uint4*)(hp + (size_t)(unsigned)s0 * ROWE);
        if (e + 1 < dg) u1 = *(const uint4*)(hp + (size_t)(unsigned)s1 * ROWE);
        if (e + 2 < dg) u2 = *(const uint4*)(hp + (size_t)(unsigned)s2 * ROWE);
        if (e + 3 < dg) u3 = *(const uint4*)(hp + (size_t)(unsigned)s3 * ROWE);
        if (e + 4 < dg) u4 = *(const uint4*)(hp + (size_t)(unsigned)s4 * ROWE);
        if (e + 5 < dg) u5 = *(const uint4*)(hp + (size_t)(unsigned)s5 * ROWE);
        if (e + 6 < dg) u6 = *(const uint4*)(hp + (size_t)(unsigned)s6 * ROWE);
        if (e + 7 < dg) u7 = *(const uint4*)(hp + (size_t)(unsigned)s7 * ROWE);
        CVT16(u0) CVT16(u1) CVT16(u2) CVT16(u3)
        CVT16(u4) CVT16(u5) CVT16(u6) CVT16(u7)
    }
    #undef CVT16

    if (nv) {
        unsigned short* op = agg + (size_t)nid * ROWE + sub * 16;
        *(ushort4*)(op)      = make_ushort4(f2b(a[0]),  f2b(a[1]),  f2b(a[2]),  f2b(a[3]));
        *(ushort4*)(op + 4)  = make_ushort4(f2b(a[4]),  f2b(a[5]),  f2b(a[6]),  f2b(a[7]));
        *(ushort4*)(op + 8)  = make_ushort4(f2b(a[8]),  f2b(a[9]),  f2b(a[10]), f2b(a[11]));
        *(ushort4*)(op + 12) = make_ushort4(f2b(a[12]), f2b(a[13]), f2b(a[14]), f2b(a[15]));
    }
}

// ---------------------------------------------------------------------------
// abs + per-graph sum over final z [N,64]c bf16 (row = 128 ushorts).
// ---------------------------------------------------------------------------
__global__ __launch_bounds__(256) void abs_reduce_kernel(
    const unsigned short* __restrict__ z, const int* __restrict__ batch,
    float* __restrict__ sums, int N)
{
    constexpr int NPW = 16;
    int wid  = (blockIdx.x * 256 + threadIdx.x) >> 6;
    int lane = threadIdx.x & 63;
    int nBeg = wid * NPW;
    if (nBeg >= N) return;
    int nEnd = min(nBeg + NPW, N);

    float acc = 0.f;
    int cur_g = batch[nBeg];
    for (int n = nBeg; n < nEnd; ++n) {
        unsigned int u = *(const unsigned int*)(z + ((size_t)n << 7) + (lane << 1));
        float zr = b2f((unsigned short)(u & 0xffffu));
        float zi = b2f((unsigned short)(u >> 16));
        float a = sqrtf(zr * zr + zi * zi);
        int g = batch[n];
        if (g != cur_g) {
            if ((unsigned)cur_g < 64u) unsafeAtomicAdd(&sums[cur_g * 64 + lane], acc);
            acc = 0.f;
            cur_g = g;
        }
        acc += a;
    }
    if ((unsigned)cur_g < 64u) unsafeAtomicAdd(&sums[cur_g * 64 + lane], acc);
}

// per-graph count via binary search (batch sorted) + mean + log_softmax
__global__ __launch_bounds__(64) void finalize_kernel(
    const float* __restrict__ sums, const int* __restrict__ batch,
    float* __restrict__ out, int N)
{
    int g = blockIdx.x, d = threadIdx.x;
    __shared__ int cnt_s;
    if (d == 0) {
        int lo = 0, hi = N;
        while (lo < hi) { int mid = (lo + hi) >> 1; if (batch[mid] < g) lo = mid + 1; else hi = mid; }
        int lo2 = lo, hi2 = N;
        while (lo2 < hi2) { int mid = (lo2 + hi2) >> 1; if (batch[mid] < g + 1) lo2 = mid + 1; else hi2 = mid; }
        cnt_s = lo2 - lo;
    }
    __syncthreads();
    float c = fmaxf((float)cnt_s, 1.0f);
    float m = sums[g * 64 + d] / c;
    float mx = m;
    #pragma unroll
    for (int o = 32; o > 0; o >>= 1) mx = fmaxf(mx, __shfl_xor(mx, o, 64));
    float e = expf(m - mx);
    float s = e;
    #pragma unroll
    for (int o = 32; o > 0; o >>= 1) s += __shfl_xor(s, o, 64);
    out[g * 64 + d] = m - mx - logf(s);
}

extern "C" void kernel_launch(void* const* d_in, const int* in_sizes, int n_in,
                              void* d_out, int out_size, void* d_ws, size_t ws_size,
                              hipStream_t stream)
{
    const float* x   = (const float*)d_in[0];
    const float* W0r = (const float*)d_in[1];
    const float* W0i = (const float*)d_in[2];
    const float* b0r = (const float*)d_in[3];
    const float* b0i = (const float*)d_in[4];
    const float* M0r = (const float*)d_in[5];
    const float* M0i = (const float*)d_in[6];
    const float* c0r = (const float*)d_in[7];
    const float* c0i = (const float*)d_in[8];
    const float* t0r = (const float*)d_in[9];
    const float* t0i = (const float*)d_in[10];
    const float* W1r = (const float*)d_in[11];
    const float* W1i = (const float*)d_in[12];
    const float* b1r = (const float*)d_in[13];
    const float* b1i = (const float*)d_in[14];
    const float* M1r = (const float*)d_in[15];
    const float* M1i = (const float*)d_in[16];
    const float* c1r = (const float*)d_in[17];
    const float* c1i = (const float*)d_in[18];
    const float* t1r = (const float*)d_in[19];
    const float* t1i = (const float*)d_in[20];
    const int* edge  = (const int*)d_in[21];
    const int* batch = (const int*)d_in[22];

    const int N = in_sizes[0] / 128;
    const int E = in_sizes[21] / 2;
    const int* src = edge;
    const int* dst = edge + E;

    // ---- workspace (~206 MB) ----
    unsigned short* h0   = (unsigned short*)d_ws;       // becomes x1, in place
    unsigned short* aggA = h0 + (size_t)N * 256;
    unsigned short* h1   = aggA + (size_t)N * 256;      // becomes z, in place
    unsigned short* aggB = h1 + (size_t)N * 128;
    int*   deg  = (int*)(aggB + (size_t)N * 128);
    int*   csr  = deg + N;
    float* sums = (float*)(csr + (size_t)N * 64);
    unsigned short* V0  = (unsigned short*)(sums + 4096);  // [256,128]
    unsigned short* VM0 = V0  + 256 * 128;                 // [256,256]
    unsigned short* V1  = VM0 + 256 * 256;                 // [128,256]
    unsigned short* VM1 = V1  + 128 * 256;                 // [128,128]
    // fp8 gather payload; h0f8 (N*256B) and h1f8 (N*128B) share one region.
    unsigned char* hf8 = (unsigned char*)(VM1 + 128 * 128);

    const int gemmGrid  = (N + 63) / 64;
    const int buildGrid = ((E + EDGE_CHUNK - 1) / EDGE_CHUNK) * 8;
    const int pbGrid    = 176 + buildGrid;
    const int g256Grid  = (N + 15) / 16;   // 4 nodes/wave, 4 waves/block
    const int g128Grid  = (N + 31) / 32;   // 8 nodes/wave, 4 waves/block
    const int wave16Grid = ((N + 15) / 16 * 64 + 255) / 256;

    // ---- zero deg/sums (DMA, stream-ordered), then fused prep+build ----
    hipMemsetAsync(deg, 0, N * sizeof(int), stream);
    hipMemsetAsync(sums, 0, 4096 * sizeof(float), stream);
    prep_build_kernel<<<pbGrid, 256, 0, stream>>>(
        W0r, W0i, V0, M0r, M0i, VM0, W1r, W1i, V1, M1r, M1i, VM1,
        src, dst, deg, csr, E, N);

    // ---- layer 0 ----
    mfma_cgemm_kernel<128,256,0,true,false,true><<<gemmGrid, 256, 0, stream>>>(
        x, V0, b0r, b0i, nullptr, nullptr, nullptr, nullptr, h0, hf8, N);
    gather_f8_kernel<256><<<g256Grid, 256, 0, stream>>>(hf8, aggA, deg, csr, N);
    mfma_cgemm_kernel<256,256,1,false,true,false><<<gemmGrid, 256, 0, stream>>>(
        aggA, VM0, c0r, c0i, t0r, t0i, h0, deg, h0, nullptr, N);

    // ---- layer 1 ----
    mfma_cgemm_kernel<256,128,1,true,false,true><<<gemmGrid, 256, 0, stream>>>(
        h0, V1, b1r, b1i, nullptr, nullptr, nullptr, nullptr, h1, hf8, N);
    gather_f8_kernel<128><<<g128Grid, 256, 0, stream>>>(hf8, aggB, deg, csr, N);
    mfma_cgemm_kernel<128,128,1,false,true,false><<<gemmGrid, 256, 0, stream>>>(
        aggB, VM1, c1r, c1i, t1r, t1i, h1, deg, h1, nullptr, N);

    // ---- readout ----
    abs_reduce_kernel<<<wave16Grid, 256, 0, stream>>>(h1, batch, sums, N);
    finalize_kernel<<<64, 64, 0, stream>>>(sums, batch, (float*)d_out, N);
}

// Round 12
// 476.405 us; speedup vs baseline: 1.0431x; 1.0338x over previous
//
#include <hip/hip_runtime.h>

typedef __attribute__((ext_vector_type(8))) short bf16x8;
typedef __attribute__((ext_vector_type(4))) float f32x4;

// ---- bf16 (as ushort) helpers ----
__device__ __forceinline__ float b2f(unsigned short u) {
    return __uint_as_float(((unsigned int)u) << 16);
}
__device__ __forceinline__ unsigned short f2b(float f) {
    unsigned int u = __float_as_uint(f);
    unsigned int r = (u + 0x7FFFu + ((u >> 16) & 1u)) >> 16;   // RNE
    return (unsigned short)r;
}

#define EDGE_CHUNK 2048

// ---------------------------------------------------------------------------
// prep_build (round 20 — proven: prep fully hidden under build, 84 us).
// ---------------------------------------------------------------------------
__global__ __launch_bounds__(256) void prep_build_kernel(
    const float* __restrict__ W0r, const float* __restrict__ W0i, unsigned short* __restrict__ V0,
    const float* __restrict__ M0r, const float* __restrict__ M0i, unsigned short* __restrict__ VM0,
    const float* __restrict__ W1r, const float* __restrict__ W1i, unsigned short* __restrict__ V1,
    const float* __restrict__ M1r, const float* __restrict__ M1i, unsigned short* __restrict__ VM1,
    const int* __restrict__ src, const int* __restrict__ dst,
    int* __restrict__ deg, int* __restrict__ csr, int E, int N)
{
    int b = blockIdx.x;
    if (b < 64) {                       // V0 real
        int idx = b * 256 + threadIdx.x;
        int j = idx >> 7, k = idx & 127;
        V0[(size_t)(2 * j) * 128 + k]     = f2b(W0r[idx]);
        V0[(size_t)(2 * j + 1) * 128 + k] = f2b(W0i[idx]);
    } else if (b < 128) {               // VM0 cplx
        int idx = (b - 64) * 256 + threadIdx.x;
        int j = idx >> 7, kk = idx & 127;
        float wr = M0r[idx], wi = M0i[idx];
        unsigned short* r0 = VM0 + (size_t)(2 * j) * 256 + 2 * kk;
        unsigned short* r1 = VM0 + (size_t)(2 * j + 1) * 256 + 2 * kk;
        r0[0] = f2b(wr);  r0[1] = f2b(-wi);
        r1[0] = f2b(wi);  r1[1] = f2b(wr);
    } else if (b < 160) {               // V1 cplx
        int idx = (b - 128) * 256 + threadIdx.x;
        int j = idx >> 7, kk = idx & 127;
        float wr = W1r[idx], wi = W1i[idx];
        unsigned short* r0 = V1 + (size_t)(2 * j) * 256 + 2 * kk;
        unsigned short* r1 = V1 + (size_t)(2 * j + 1) * 256 + 2 * kk;
        r0[0] = f2b(wr);  r0[1] = f2b(-wi);
        r1[0] = f2b(wi);  r1[1] = f2b(wr);
    } else if (b < 176) {               // VM1 cplx
        int idx = (b - 160) * 256 + threadIdx.x;
        int j = idx >> 6, kk = idx & 63;
        float wr = M1r[idx], wi = M1i[idx];
        unsigned short* r0 = VM1 + (size_t)(2 * j) * 128 + 2 * kk;
        unsigned short* r1 = VM1 + (size_t)(2 * j + 1) * 128 + 2 * kk;
        r0[0] = f2b(wr);  r0[1] = f2b(-wi);
        r1[0] = f2b(wi);  r1[1] = f2b(wr);
    } else {                            // bucket-CSR build
        int vb = b - 176;
        int x  = vb & 7;
        int c  = vb >> 3;
        int lo = (int)((long long)N * x / 8);
        int hi = (int)((long long)N * (x + 1) / 8);
        int base = c * EDGE_CHUNK;
        int end  = min(base + EDGE_CHUNK, E);
        for (int e = base + threadIdx.x; e < end; e += 256) {
            int d = __builtin_nontemporal_load(dst + e);
            if (d >= lo && d < hi) {
                int s = __builtin_nontemporal_load(src + e);
                if ((unsigned)s < (unsigned)N) {
                    int pos = atomicAdd(&deg[d], 1);
                    if (pos < 64) csr[((size_t)d << 6) + pos] = s;
                }
            }
        }
    }
}

// ---------------------------------------------------------------------------
// MFMA complex GEMM as real GEMM (round 13 wave partition).
// AMODE: 0 = fp32 real input, 1 = bf16 cplx input.
// WF8: non-MIX epilogue also emits fp8(e4m3) gather payload.
// ---------------------------------------------------------------------------
template<int Kr, int TWOJ, int AMODE, bool CRELU, bool MIX, bool WF8>
__global__ __launch_bounds__(256) void mfma_cgemm_kernel(
    const void* __restrict__ Xv,
    const unsigned short* __restrict__ Vg,
    const float* __restrict__ br, const float* __restrict__ bi,
    const float* __restrict__ trp, const float* __restrict__ tip,
    const unsigned short* __restrict__ Hin, const int* __restrict__ degp,
    unsigned short* __restrict__ Out, unsigned char* __restrict__ Of8,
    int nNodes)
{
    constexpr int TILES  = TWOJ / 16;
    constexpr int FT     = TILES / 4;   // feature tiles per wave
    constexpr int CHUNKS = Kr / 32;
    constexpr int VROW   = 40;          // 80B row stride (16B-aligned)
    static_assert(TILES % 4 == 0, "TILES % 4");

    __shared__ __align__(16) unsigned short sV[TWOJ * VROW];
    __shared__ __align__(16) unsigned short sA[64 * VROW];

    const int tid  = threadIdx.x;
    const int w    = tid >> 6;
    const int lane = tid & 63;
    const int l15  = lane & 15;
    const int q    = lane >> 4;
    const int n0   = blockIdx.x * 64;
    const int tq   = w * FT;            // this wave's first feature tile

    f32x4 acc[FT][4];
    #pragma unroll
    for (int t = 0; t < FT; ++t)
        #pragma unroll
        for (int nt = 0; nt < 4; ++nt) acc[t][nt] = (f32x4){0.f, 0.f, 0.f, 0.f};

    for (int kc = 0; kc < CHUNKS; ++kc) {
        // ---- stage V chunk ----
        #pragma unroll
        for (int it = 0; it < TWOJ / 64; ++it) {
            int idx = it * 256 + tid;
            int row = idx >> 2;
            int seg = idx & 3;
            *(uint4*)(sV + row * VROW + seg * 8) =
                *(const uint4*)(Vg + (size_t)row * Kr + kc * 32 + seg * 8);
        }
        // ---- stage A chunk ----
        if constexpr (AMODE == 0) {
            const float* X = (const float*)Xv;
            #pragma unroll
            for (int it = 0; it < 2; ++it) {
                int idx = it * 256 + tid;
                int nl = idx >> 3;
                int cg = idx & 7;
                int n  = n0 + nl;
                f32x4 v = (f32x4){0.f, 0.f, 0.f, 0.f};
                if (n < nNodes)
                    v = __builtin_nontemporal_load(
                        (const f32x4*)(X + (size_t)n * Kr + kc * 32 + cg * 4));
                *(ushort4*)(sA + nl * VROW + cg * 4) =
                    make_ushort4(f2b(v[0]), f2b(v[1]), f2b(v[2]), f2b(v[3]));
            }
        } else {
            const unsigned short* X = (const unsigned short*)Xv;
            int nl  = tid >> 2;
            int seg = tid & 3;
            int n   = n0 + nl;
            uint4 v = make_uint4(0, 0, 0, 0);
            if (n < nNodes)
                v = *(const uint4*)(X + (size_t)n * Kr + kc * 32 + seg * 8);
            *(uint4*)(sA + nl * VROW + seg * 8) = v;
        }
        __syncthreads();

        // ---- inner: 4 bfrags reused across FT afrags ----
        bf16x8 bfrag[4];
        #pragma unroll
        for (int nt = 0; nt < 4; ++nt)
            bfrag[nt] = *(const bf16x8*)(sA + (nt * 16 + l15) * VROW + q * 8);
        #pragma unroll
        for (int t = 0; t < FT; ++t) {
            bf16x8 afrag = *(const bf16x8*)(sV + ((tq + t) * 16 + l15) * VROW + q * 8);
            #pragma unroll
            for (int nt = 0; nt < 4; ++nt)
                acc[t][nt] = __builtin_amdgcn_mfma_f32_16x16x32_bf16(
                    afrag, bfrag[nt], acc[t][nt], 0, 0, 0);
        }
        __syncthreads();
    }

    // ---- epilogue ----
    float Fr = 1.f, Fi = 0.f, efr = 1.f, efi = 0.f;
    if constexpr (MIX) {
        float tr = trp[0], ti = tip[0];
        float er  = expf(ti);
        float tfr =  er * cosf(tr);
        float tfi = -er * sinf(tr);
        float eh  = expf(0.5f * ti);
        efr =  eh * cosf(0.5f * tr);
        efi = -eh * sinf(0.5f * tr);
        float omr = 1.f - efr, omi = -efi;
        Fr = tfr * omr - tfi * omi;
        Fi = tfr * omi + tfi * omr;
    }
    #pragma unroll
    for (int nt = 0; nt < 4; ++nt) {
        int n = n0 + nt * 16 + l15;
        if (n >= nNodes) continue;
        float dg = 0.f;
        if constexpr (MIX) dg = (float)degp[n];
        #pragma unroll
        for (int t = 0; t < FT; ++t) {
            int f0 = (tq + t) * 16 + q * 4;
            int j0 = f0 >> 1;
            float re0, im0, re1, im1;
            if constexpr (MIX) {
                float ar0 = acc[t][nt][0] + dg * br[j0];
                float ai0 = acc[t][nt][1] + dg * bi[j0];
                float ar1 = acc[t][nt][2] + dg * br[j0 + 1];
                float ai1 = acc[t][nt][3] + dg * bi[j0 + 1];
                re0 = ar0 * Fr - ai0 * Fi;  im0 = ar0 * Fi + ai0 * Fr;
                re1 = ar1 * Fr - ai1 * Fi;  im1 = ar1 * Fi + ai1 * Fr;
                ushort4 hu = *(const ushort4*)(Hin + (size_t)n * TWOJ + f0);
                float hr0 = b2f(hu.x), hi0 = b2f(hu.y), hr1 = b2f(hu.z), hi1 = b2f(hu.w);
                re0 += hr0 * efr - hi0 * efi;  im0 += hr0 * efi + hi0 * efr;
                re1 += hr1 * efr - hi1 * efi;  im1 += hr1 * efi + hi1 * efr;
            } else {
                re0 = acc[t][nt][0] + br[j0];
                im0 = acc[t][nt][1] + bi[j0];
                re1 = acc[t][nt][2] + br[j0 + 1];
                im1 = acc[t][nt][3] + bi[j0 + 1];
                if constexpr (CRELU) {
                    re0 = fmaxf(re0, 0.f); im0 = fmaxf(im0, 0.f);
                    re1 = fmaxf(re1, 0.f); im1 = fmaxf(im1, 0.f);
                }
            }
            *(ushort4*)(Out + (size_t)n * TWOJ + f0) =
                make_ushort4(f2b(re0), f2b(im0), f2b(re1), f2b(im1));
            if constexpr (WF8) {
                int pk = 0;
                pk = __builtin_amdgcn_cvt_pk_fp8_f32(re0, im0, pk, false);
                pk = __builtin_amdgcn_cvt_pk_fp8_f32(re1, im1, pk, true);
                *(int*)(Of8 + (size_t)n * TWOJ + f0) = pk;
            }
        }
    }
}

// ---------------------------------------------------------------------------
// Fused GEMM2+GEMM3 (round 22): phase 1 computes x1 = MIX(aggA@VM0, h0) into
// LDS (never touches HBM — kills the 51.2 MB x1 write + 51.2 MB re-read);
// phase 2 computes h1 = crelu(x1 @ V1^T + b1) + fp8 payload from LDS.
// x1 stored chunked [kc][64][VROW] so phase-2 fragment reads are the exact
// proven sA pattern. Homogeneous fusion — no round-6 occupancy trap.
// LDS ~65 KB -> 2 blocks/CU.
// ---------------------------------------------------------------------------
__global__ __launch_bounds__(256) void mfma_dual_kernel(
    const unsigned short* __restrict__ Xagg,   // aggA bf16 [N,256]
    const unsigned short* __restrict__ VM,     // VM0 [256,256]
    const unsigned short* __restrict__ Vg2,    // V1  [128,256]
    const float* __restrict__ cr, const float* __restrict__ ci,
    const float* __restrict__ trp, const float* __restrict__ tip,
    const float* __restrict__ b1r, const float* __restrict__ b1i,
    const unsigned short* __restrict__ Hin,    // h0 [N,256]
    const int* __restrict__ degp,
    unsigned short* __restrict__ Out,          // h1 [N,128]
    unsigned char* __restrict__ Of8,           // hf8 [N,128]
    int nNodes)
{
    constexpr int VROW = 40;
    __shared__ __align__(16) unsigned short sV[256 * VROW];
    __shared__ __align__(16) unsigned short sA[64 * VROW];
    __shared__ __align__(16) unsigned short x1b[8 * 64 * VROW];

    const int tid  = threadIdx.x;
    const int w    = tid >> 6;
    const int lane = tid & 63;
    const int l15  = lane & 15;
    const int q    = lane >> 4;
    const int n0   = blockIdx.x * 64;

    // ================= phase 1: x1 = MIX(aggA @ VM0, h0) =================
    {
        f32x4 acc[4][4];
        #pragma unroll
        for (int t = 0; t < 4; ++t)
            #pragma unroll
            for (int nt = 0; nt < 4; ++nt) acc[t][nt] = (f32x4){0.f, 0.f, 0.f, 0.f};

        for (int kc = 0; kc < 8; ++kc) {
            #pragma unroll
            for (int it = 0; it < 4; ++it) {
                int idx = it * 256 + tid;
                int row = idx >> 2;
                int seg = idx & 3;
                *(uint4*)(sV + row * VROW + seg * 8) =
                    *(const uint4*)(VM + (size_t)row * 256 + kc * 32 + seg * 8);
            }
            {
                int nl  = tid >> 2;
                int seg = tid & 3;
                int n   = n0 + nl;
                uint4 v = make_uint4(0, 0, 0, 0);
                if (n < nNodes)
                    v = *(const uint4*)(Xagg + (size_t)n * 256 + kc * 32 + seg * 8);
                *(uint4*)(sA + nl * VROW + seg * 8) = v;
            }
            __syncthreads();
            bf16x8 bfrag[4];
            #pragma unroll
            for (int nt = 0; nt < 4; ++nt)
                bfrag[nt] = *(const bf16x8*)(sA + (nt * 16 + l15) * VROW + q * 8);
            #pragma unroll
            for (int t = 0; t < 4; ++t) {
                bf16x8 afrag = *(const bf16x8*)(sV + ((w * 4 + t) * 16 + l15) * VROW + q * 8);
                #pragma unroll
                for (int nt = 0; nt < 4; ++nt)
                    acc[t][nt] = __builtin_amdgcn_mfma_f32_16x16x32_bf16(
                        afrag, bfrag[nt], acc[t][nt], 0, 0, 0);
            }
            __syncthreads();
        }

        // MIX factors
        float tr = trp[0], ti = tip[0];
        float er  = expf(ti);
        float tfr =  er * cosf(tr);
        float tfi = -er * sinf(tr);
        float eh  = expf(0.5f * ti);
        float efr =  eh * cosf(0.5f * tr);
        float efi = -eh * sinf(0.5f * tr);
        float omr = 1.f - efr, omi = -efi;
        float Fr = tfr * omr - tfi * omi;
        float Fi = tfr * omi + tfi * omr;

        // epilogue 1 -> x1b (LDS), chunked [f0>>5][node][f0&31]
        #pragma unroll
        for (int nt = 0; nt < 4; ++nt) {
            int n = n0 + nt * 16 + l15;
            if (n >= nNodes) continue;
            float dg = (float)degp[n];
            #pragma unroll
            for (int t = 0; t < 4; ++t) {
                int f0 = (w * 4 + t) * 16 + q * 4;
                int j0 = f0 >> 1;
                float ar0 = acc[t][nt][0] + dg * cr[j0];
                float ai0 = acc[t][nt][1] + dg * ci[j0];
                float ar1 = acc[t][nt][2] + dg * cr[j0 + 1];
                float ai1 = acc[t][nt][3] + dg * ci[j0 + 1];
                float re0 = ar0 * Fr - ai0 * Fi, im0 = ar0 * Fi + ai0 * Fr;
                float re1 = ar1 * Fr - ai1 * Fi, im1 = ar1 * Fi + ai1 * Fr;
                ushort4 hu = *(const ushort4*)(Hin + (size_t)n * 256 + f0);
                float hr0 = b2f(hu.x), hi0 = b2f(hu.y), hr1 = b2f(hu.z), hi1 = b2f(hu.w);
                re0 += hr0 * efr - hi0 * efi;  im0 += hr0 * efi + hi0 * efr;
                re1 += hr1 * efr - hi1 * efi;  im1 += hr1 * efi + hi1 * efr;
                *(ushort4*)(x1b + ((f0 >> 5) * 64 + nt * 16 + l15) * VROW + (f0 & 31)) =
                    make_ushort4(f2b(re0), f2b(im0), f2b(re1), f2b(im1));
            }
        }
    }
    __syncthreads();

    // ================= phase 2: h1 = crelu(x1 @ V1 + b1) =================
    f32x4 acc2[2][4];
    #pragma unroll
    for (int t = 0; t < 2; ++t)
        #pragma unroll
        for (int nt = 0; nt < 4; ++nt) acc2[t][nt] = (f32x4){0.f, 0.f, 0.f, 0.f};

    for (int kc = 0; kc < 8; ++kc) {
        #pragma unroll
        for (int it = 0; it < 2; ++it) {
            int idx = it * 256 + tid;
            int row = idx >> 2;
            int seg = idx & 3;
            *(uint4*)(sV + row * VROW + seg * 8) =
                *(const uint4*)(Vg2 + (size_t)row * 256 + kc * 32 + seg * 8);
        }
        __syncthreads();
        bf16x8 bfrag[4];
        #pragma unroll
        for (int nt = 0; nt < 4; ++nt)
            bfrag[nt] = *(const bf16x8*)(x1b + ((size_t)(kc * 64 + nt * 16 + l15)) * VROW + q * 8);
        #pragma unroll
        for (int t = 0; t < 2; ++t) {
            bf16x8 afrag = *(const bf16x8*)(sV + ((w * 2 + t) * 16 + l15) * VROW + q * 8);
            #pragma unroll
            for (int nt = 0; nt < 4; ++nt)
                acc2[t][nt] = __builtin_amdgcn_mfma_f32_16x16x32_bf16(
                    afrag, bfrag[nt], acc2[t][nt], 0, 0, 0);
        }
        __syncthreads();
    }

    // epilogue 2: CRELU + h1 + fp8 payload
    #pragma unroll
    for (int nt = 0; nt < 4; ++nt) {
        int n = n0 + nt * 16 + l15;
        if (n >= nNodes) continue;
        #pragma unroll
        for (int t = 0; t < 2; ++t) {
            int f0 = (w * 2 + t) * 16 + q * 4;
            int j0 = f0 >> 1;
            float re0 = fmaxf(acc2[t][nt][0] + b1r[j0], 0.f);
            float im0 = fmaxf(acc2[t][nt][1] + b1i[j0], 0.f);
            float re1 = fmaxf(acc2[t][nt][2] + b1r[j0 + 1], 0.f);
            float im1 = fmaxf(acc2[t][nt][3] + b1i[j0 + 1], 0.f);
            *(ushort4*)(Out + (size_t)n * 128 + f0) =
                make_ushort4(f2b(re0), f2b(im0), f2b(re1), f2b(im1));
            int pk = 0;
            pk = __builtin_amdgcn_cvt_pk_fp8_f32(re0, im0, pk, false);
            pk = __builtin_amdgcn_cvt_pk_fp8_f32(re1, im1, pk, true);
            *(int*)(Of8 + (size_t)n * 128 + f0) = pk;
        }
    }
}

// ---------------------------------------------------------------------------
// Gather-sum, fp8 payload IN, bf16 agg OUT; node-per-lane-group (round 15).
// ---------------------------------------------------------------------------
template<int ROWE>
__global__ __launch_bounds__(256) void gather_f8_kernel(
    const unsigned char* __restrict__ h8, unsigned short* __restrict__ agg,
    const int* __restrict__ deg, const int* __restrict__ csr, int N)
{
    constexpr int LPR = ROWE / 16;   // lanes per node: 16 or 8
    constexpr int NPW = 64 / LPR;    // nodes per wave: 4 or 8
    const int tid  = threadIdx.x;
    const int lane = tid & 63;
    const int wid  = (blockIdx.x * 256 + tid) >> 6;
    if (wid * NPW >= N) return;
    const int g    = lane / LPR;
    const int sub  = lane % LPR;
    const int nid  = wid * NPW + g;
    const bool nv  = nid < N;
    int dg = 0;
    if (nv) dg = min(deg[nid], 64);

    uint4 cq0 = make_uint4(0, 0, 0, 0), cq1 = make_uint4(0, 0, 0, 0);
    if (nv) {
        const uint4* cp = (const uint4*)csr + ((size_t)nid << 4);
        cq0 = cp[sub];
        if constexpr (LPR == 8) cq1 = cp[8 + sub];
    }

    int mx = dg;
    mx = max(mx, __shfl_xor(mx, 32, 64));
    mx = max(mx, __shfl_xor(mx, 16, 64));
    if constexpr (LPR == 8) mx = max(mx, __shfl_xor(mx, 8, 64));

    float a[16];
    #pragma unroll
    for (int k = 0; k < 16; ++k) a[k] = 0.f;

    const unsigned char* hp = h8 + sub * 16;
    const int gb = g * LPR;

    #define CVT16(uu)                                                          \
        {                                                                      \
            auto p0 = __builtin_amdgcn_cvt_pk_f32_fp8((uu).x, false);          \
            a[0] += p0[0];   a[1] += p0[1];                                    \
            auto p1 = __builtin_amdgcn_cvt_pk_f32_fp8((uu).x, true);           \
            a[2] += p1[0];   a[3] += p1[1];                                    \
            auto p2 = __builtin_amdgcn_cvt_pk_f32_fp8((uu).y, false);          \
            a[4] += p2[0];   a[5] += p2[1];                                    \
            auto p3 = __builtin_amdgcn_cvt_pk_f32_fp8((uu).y, true);           \
            a[6] += p3[0];   a[7] += p3[1];                                    \
            auto p4 = __builtin_amdgcn_cvt_pk_f32_fp8((uu).z, false);          \
            a[8] += p4[0];   a[9] += p4[1];                                    \
            auto p5 = __builtin_amdgcn_cvt_pk_f32_fp8((uu).z, true);           \
            a[10] += p5[0];  a[11] += p5[1];                                   \
            auto p6 = __builtin_amdgcn_cvt_pk_f32_fp8((uu).w, false);          \
            a[12] += p6[0];  a[13] += p6[1];                                   \
            auto p7 = __builtin_amdgcn_cvt_pk_f32_fp8((uu).w, true);           \
            a[14] += p7[0];  a[15] += p7[1];                                   \
        }

    for (int e = 0; e < mx; e += 8) {
        uint4 cq = cq0;
        if constexpr (LPR == 8) { if (e & 32) cq = cq1; }
        const int o0 = gb + ((e & (4 * LPR - 1)) >> 2);
        const int o1 = o0 + 1;
        int s0 = __shfl((int)cq.x, o0, 64);
        int s1 = __shfl((int)cq.y, o0, 64);
        int s2 = __shfl((int)cq.z, o0, 64);
        int s3 = __shfl((int)cq.w, o0, 64);
        int s4 = __shfl((int)cq.x, o1, 64);
        int s5 = __shfl((int)cq.y, o1, 64);
        int s6 = __shfl((int)cq.z, o1, 64);
        int s7 = __shfl((int)cq.w, o1, 64);
        uint4 u0 = make_uint4(0,0,0,0), u1 = make_uint4(0,0,0,0);
        uint4 u2 = make_uint4(0,0,0,0), u3 = make_uint4(0,0,0,0);
        uint4 u4 = make_uint4(0,0,0,0), u5 = make_uint4(0,0,0,0);
        uint4 u6 = make_uint4(0,0,0,0), u7 = make_uint4(0,0,0,0);
        if (e + 0 < dg) u0 = *(const uint4*)(hp + (size_t)(unsigned)s0 * ROWE);
        if (e + 1 < dg) u1 = *(const uint4*)(hp + (size_t)(unsigned)s1 * ROWE);
        if (e + 2 < dg) u2 = *(const uint4*)(hp + (size_t)(unsigned)s2 * ROWE);
        if (e + 3 < dg) u3 = *(const uint4*)(hp + (size_t)(unsigned)s3 * ROWE);
        if (e + 4 < dg) u4 = *(const uint4*)(hp + (size_t)(unsigned)s4 * ROWE);
        if (e + 5 < dg) u5 = *(const uint4*)(hp + (size_t)(unsigned)s5 * ROWE);
        if (e + 6 < dg) u6 = *(const uint4*)(hp + (size_t)(unsigned)s6 * ROWE);
        if (e + 7 < dg) u7 = *(const uint4*)(hp + (size_t)(unsigned)s7 * ROWE);
        CVT16(u0) CVT16(u1) CVT16(u2) CVT16(u3)
        CVT16(u4) CVT16(u5) CVT16(u6) CVT16(u7)
    }
    #undef CVT16

    if (nv) {
        unsigned short* op = agg + (size_t)nid * ROWE + sub * 16;
        *(ushort4*)(op)      = make_ushort4(f2b(a[0]),  f2b(a[1]),  f2b(a[2]),  f2b(a[3]));
        *(ushort4*)(op + 4)  = make_ushort4(f2b(a[4]),  f2b(a[5]),  f2b(a[6]),  f2b(a[7]));
        *(ushort4*)(op + 8)  = make_ushort4(f2b(a[8]),  f2b(a[9]),  f2b(a[10]), f2b(a[11]));
        *(ushort4*)(op + 12) = make_ushort4(f2b(a[12]), f2b(a[13]), f2b(a[14]), f2b(a[15]));
    }
}

// ---------------------------------------------------------------------------
// abs + per-graph sum over final z [N,64]c bf16 (row = 128 ushorts).
// ---------------------------------------------------------------------------
__global__ __launch_bounds__(256) void abs_reduce_kernel(
    const unsigned short* __restrict__ z, const int* __restrict__ batch,
    float* __restrict__ sums, int N)
{
    constexpr int NPW = 16;
    int wid  = (blockIdx.x * 256 + threadIdx.x) >> 6;
    int lane = threadIdx.x & 63;
    int nBeg = wid * NPW;
    if (nBeg >= N) return;
    int nEnd = min(nBeg + NPW, N);

    float acc = 0.f;
    int cur_g = batch[nBeg];
    for (int n = nBeg; n < nEnd; ++n) {
        unsigned int u = *(const unsigned int*)(z + ((size_t)n << 7) + (lane << 1));
        float zr = b2f((unsigned short)(u & 0xffffu));
        float zi = b2f((unsigned short)(u >> 16));
        float a = sqrtf(zr * zr + zi * zi);
        int g = batch[n];
        if (g != cur_g) {
            if ((unsigned)cur_g < 64u) unsafeAtomicAdd(&sums[cur_g * 64 + lane], acc);
            acc = 0.f;
            cur_g = g;
        }
        acc += a;
    }
    if ((unsigned)cur_g < 64u) unsafeAtomicAdd(&sums[cur_g * 64 + lane], acc);
}

// per-graph count via binary search (batch sorted) + mean + log_softmax
__global__ __launch_bounds__(64) void finalize_kernel(
    const float* __restrict__ sums, const int* __restrict__ batch,
    float* __restrict__ out, int N)
{
    int g = blockIdx.x, d = threadIdx.x;
    __shared__ int cnt_s;
    if (d == 0) {
        int lo = 0, hi = N;
        while (lo < hi) { int mid = (lo + hi) >> 1; if (batch[mid] < g) lo = mid + 1; else hi = mid; }
        int lo2 = lo, hi2 = N;
        while (lo2 < hi2) { int mid = (lo2 + hi2) >> 1; if (batch[mid] < g + 1) lo2 = mid + 1; else hi2 = mid; }
        cnt_s = lo2 - lo;
    }
    __syncthreads();
    float c = fmaxf((float)cnt_s, 1.0f);
    float m = sums[g * 64 + d] / c;
    float mx = m;
    #pragma unroll
    for (int o = 32; o > 0; o >>= 1) mx = fmaxf(mx, __shfl_xor(mx, o, 64));
    float e = expf(m - mx);
    float s = e;
    #pragma unroll
    for (int o = 32; o > 0; o >>= 1) s += __shfl_xor(s, o, 64);
    out[g * 64 + d] = m - mx - logf(s);
}

extern "C" void kernel_launch(void* const* d_in, const int* in_sizes, int n_in,
                              void* d_out, int out_size, void* d_ws, size_t ws_size,
                              hipStream_t stream)
{
    const float* x   = (const float*)d_in[0];
    const float* W0r = (const float*)d_in[1];
    const float* W0i = (const float*)d_in[2];
    const float* b0r = (const float*)d_in[3];
    const float* b0i = (const float*)d_in[4];
    const float* M0r = (const float*)d_in[5];
    const float* M0i = (const float*)d_in[6];
    const float* c0r = (const float*)d_in[7];
    const float* c0i = (const float*)d_in[8];
    const float* t0r = (const float*)d_in[9];
    const float* t0i = (const float*)d_in[10];
    const float* W1r = (const float*)d_in[11];
    const float* W1i = (const float*)d_in[12];
    const float* b1r = (const float*)d_in[13];
    const float* b1i = (const float*)d_in[14];
    const float* M1r = (const float*)d_in[15];
    const float* M1i = (const float*)d_in[16];
    const float* c1r = (const float*)d_in[17];
    const float* c1i = (const float*)d_in[18];
    const float* t1r = (const float*)d_in[19];
    const float* t1i = (const float*)d_in[20];
    const int* edge  = (const int*)d_in[21];
    const int* batch = (const int*)d_in[22];

    const int N = in_sizes[0] / 128;
    const int E = in_sizes[21] / 2;
    const int* src = edge;
    const int* dst = edge + E;

    // ---- workspace (~206 MB) ----
    unsigned short* h0   = (unsigned short*)d_ws;
    unsigned short* aggA = h0 + (size_t)N * 256;
    unsigned short* h1   = aggA + (size_t)N * 256;      // becomes z, in place
    unsigned short* aggB = h1 + (size_t)N * 128;
    int*   deg  = (int*)(aggB + (size_t)N * 128);
    int*   csr  = deg + N;
    float* sums = (float*)(csr + (size_t)N * 64);
    unsigned short* V0  = (unsigned short*)(sums + 4096);  // [256,128]
    unsigned short* VM0 = V0  + 256 * 128;                 // [256,256]
    unsigned short* V1  = VM0 + 256 * 256;                 // [128,256]
    unsigned short* VM1 = V1  + 128 * 256;                 // [128,128]
    unsigned char* hf8 = (unsigned char*)(VM1 + 128 * 128);

    const int gemmGrid  = (N + 63) / 64;
    const int buildGrid = ((E + EDGE_CHUNK - 1) / EDGE_CHUNK) * 8;
    const int pbGrid    = 176 + buildGrid;
    const int g256Grid  = (N + 15) / 16;
    const int g128Grid  = (N + 31) / 32;
    const int wave16Grid = ((N + 15) / 16 * 64 + 255) / 256;

    // ---- zero deg/sums (DMA), then fused prep+build ----
    hipMemsetAsync(deg, 0, N * sizeof(int), stream);
    hipMemsetAsync(sums, 0, 4096 * sizeof(float), stream);
    prep_build_kernel<<<pbGrid, 256, 0, stream>>>(
        W0r, W0i, V0, M0r, M0i, VM0, W1r, W1i, V1, M1r, M1i, VM1,
        src, dst, deg, csr, E, N);

    // ---- layer 0 ----
    mfma_cgemm_kernel<128,256,0,true,false,true><<<gemmGrid, 256, 0, stream>>>(
        x, V0, b0r, b0i, nullptr, nullptr, nullptr, nullptr, h0, hf8, N);
    gather_f8_kernel<256><<<g256Grid, 256, 0, stream>>>(hf8, aggA, deg, csr, N);

    // ---- fused: x1 = MIX(aggA,h0) in LDS; h1 = crelu(x1 @ V1) + fp8 ----
    mfma_dual_kernel<<<gemmGrid, 256, 0, stream>>>(
        aggA, VM0, V1, c0r, c0i, t0r, t0i, b1r, b1i, h0, deg, h1, hf8, N);

    // ---- layer 1 tail ----
    gather_f8_kernel<128><<<g128Grid, 256, 0, stream>>>(hf8, aggB, deg, csr, N);
    mfma_cgemm_kernel<128,128,1,false,true,false><<<gemmGrid, 256, 0, stream>>>(
        aggB, VM1, c1r, c1i, t1r, t1i, h1, deg, h1, nullptr, N);

    // ---- readout ----
    abs_reduce_kernel<<<wave16Grid, 256, 0, stream>>>(h1, batch, sums, N);
    finalize_kernel<<<64, 64, 0, stream>>>(sums, batch, (float*)d_out, N);
}

// Round 14
// 472.284 us; speedup vs baseline: 1.0522x; 1.0087x over previous
//
#include <hip/hip_runtime.h>

typedef __attribute__((ext_vector_type(8))) short bf16x8;
typedef __attribute__((ext_vector_type(4))) float f32x4;

// ---- bf16 (as ushort) helpers ----
__device__ __forceinline__ float b2f(unsigned short u) {
    return __uint_as_float(((unsigned int)u) << 16);
}
__device__ __forceinline__ unsigned short f2b(float f) {
    unsigned int u = __float_as_uint(f);
    unsigned int r = (u + 0x7FFFu + ((u >> 16) & 1u)) >> 16;   // RNE
    return (unsigned short)r;
}

#define EDGE_CHUNK 2048

// ---------------------------------------------------------------------------
// prep_build (round 20 — proven: prep fully hidden under build, 84 us).
// ---------------------------------------------------------------------------
__global__ __launch_bounds__(256) void prep_build_kernel(
    const float* __restrict__ W0r, const float* __restrict__ W0i, unsigned short* __restrict__ V0,
    const float* __restrict__ M0r, const float* __restrict__ M0i, unsigned short* __restrict__ VM0,
    const float* __restrict__ W1r, const float* __restrict__ W1i, unsigned short* __restrict__ V1,
    const float* __restrict__ M1r, const float* __restrict__ M1i, unsigned short* __restrict__ VM1,
    const int* __restrict__ src, const int* __restrict__ dst,
    int* __restrict__ deg, int* __restrict__ csr, int E, int N)
{
    int b = blockIdx.x;
    if (b < 64) {                       // V0 real
        int idx = b * 256 + threadIdx.x;
        int j = idx >> 7, k = idx & 127;
        V0[(size_t)(2 * j) * 128 + k]     = f2b(W0r[idx]);
        V0[(size_t)(2 * j + 1) * 128 + k] = f2b(W0i[idx]);
    } else if (b < 128) {               // VM0 cplx
        int idx = (b - 64) * 256 + threadIdx.x;
        int j = idx >> 7, kk = idx & 127;
        float wr = M0r[idx], wi = M0i[idx];
        unsigned short* r0 = VM0 + (size_t)(2 * j) * 256 + 2 * kk;
        unsigned short* r1 = VM0 + (size_t)(2 * j + 1) * 256 + 2 * kk;
        r0[0] = f2b(wr);  r0[1] = f2b(-wi);
        r1[0] = f2b(wi);  r1[1] = f2b(wr);
    } else if (b < 160) {               // V1 cplx
        int idx = (b - 128) * 256 + threadIdx.x;
        int j = idx >> 7, kk = idx & 127;
        float wr = W1r[idx], wi = W1i[idx];
        unsigned short* r0 = V1 + (size_t)(2 * j) * 256 + 2 * kk;
        unsigned short* r1 = V1 + (size_t)(2 * j + 1) * 256 + 2 * kk;
        r0[0] = f2b(wr);  r0[1] = f2b(-wi);
        r1[0] = f2b(wi);  r1[1] = f2b(wr);
    } else if (b < 176) {               // VM1 cplx
        int idx = (b - 160) * 256 + threadIdx.x;
        int j = idx >> 6, kk = idx & 63;
        float wr = M1r[idx], wi = M1i[idx];
        unsigned short* r0 = VM1 + (size_t)(2 * j) * 128 + 2 * kk;
        unsigned short* r1 = VM1 + (size_t)(2 * j + 1) * 128 + 2 * kk;
        r0[0] = f2b(wr);  r0[1] = f2b(-wi);
        r1[0] = f2b(wi);  r1[1] = f2b(wr);
    } else {                            // bucket-CSR build
        int vb = b - 176;
        int x  = vb & 7;
        int c  = vb >> 3;
        int lo = (int)((long long)N * x / 8);
        int hi = (int)((long long)N * (x + 1) / 8);
        int base = c * EDGE_CHUNK;
        int end  = min(base + EDGE_CHUNK, E);
        for (int e = base + threadIdx.x; e < end; e += 256) {
            int d = __builtin_nontemporal_load(dst + e);
            if (d >= lo && d < hi) {
                int s = __builtin_nontemporal_load(src + e);
                if ((unsigned)s < (unsigned)N) {
                    int pos = atomicAdd(&deg[d], 1);
                    if (pos < 64) csr[((size_t)d << 6) + pos] = s;
                }
            }
        }
    }
}

// ---------------------------------------------------------------------------
// MFMA complex GEMM as real GEMM (round 13 wave partition).
// AMODE: 0 = fp32 real input, 1 = bf16 cplx input.
// WF8: non-MIX epilogue also emits fp8(e4m3) gather payload.
// RED (round 23): MIX epilogue computes abs in-register, block-segmented
// graph-sum via LDS + atomics — z is never written to HBM; abs_reduce
// dispatch eliminated. Per-block reduce over own outputs (no stragglers).
// ---------------------------------------------------------------------------
template<int Kr, int TWOJ, int AMODE, bool CRELU, bool MIX, bool WF8, bool RED>
__global__ __launch_bounds__(256) void mfma_cgemm_kernel(
    const void* __restrict__ Xv,
    const unsigned short* __restrict__ Vg,
    const float* __restrict__ br, const float* __restrict__ bi,
    const float* __restrict__ trp, const float* __restrict__ tip,
    const unsigned short* __restrict__ Hin, const int* __restrict__ degp,
    unsigned short* __restrict__ Out, unsigned char* __restrict__ Of8,
    const int* __restrict__ batch, float* __restrict__ sums,
    int nNodes)
{
    constexpr int TILES  = TWOJ / 16;
    constexpr int FT     = TILES / 4;   // feature tiles per wave
    constexpr int CHUNKS = Kr / 32;
    constexpr int VROW   = 40;          // 80B row stride (16B-aligned)
    static_assert(TILES % 4 == 0, "TILES % 4");
    static_assert(!RED || MIX, "RED requires MIX");

    __shared__ __align__(16) unsigned short sV[TWOJ * VROW];
    __shared__ __align__(16) unsigned short sA[64 * VROW];

    const int tid  = threadIdx.x;
    const int w    = tid >> 6;
    const int lane = tid & 63;
    const int l15  = lane & 15;
    const int q    = lane >> 4;
    const int n0   = blockIdx.x * 64;
    const int tq   = w * FT;            // this wave's first feature tile

    f32x4 acc[FT][4];
    #pragma unroll
    for (int t = 0; t < FT; ++t)
        #pragma unroll
        for (int nt = 0; nt < 4; ++nt) acc[t][nt] = (f32x4){0.f, 0.f, 0.f, 0.f};

    for (int kc = 0; kc < CHUNKS; ++kc) {
        // ---- stage V chunk ----
        #pragma unroll
        for (int it = 0; it < TWOJ / 64; ++it) {
            int idx = it * 256 + tid;
            int row = idx >> 2;
            int seg = idx & 3;
            *(uint4*)(sV + row * VROW + seg * 8) =
                *(const uint4*)(Vg + (size_t)row * Kr + kc * 32 + seg * 8);
        }
        // ---- stage A chunk ----
        if constexpr (AMODE == 0) {
            const float* X = (const float*)Xv;
            #pragma unroll
            for (int it = 0; it < 2; ++it) {
                int idx = it * 256 + tid;
                int nl = idx >> 3;
                int cg = idx & 7;
                int n  = n0 + nl;
                f32x4 v = (f32x4){0.f, 0.f, 0.f, 0.f};
                if (n < nNodes)
                    v = __builtin_nontemporal_load(
                        (const f32x4*)(X + (size_t)n * Kr + kc * 32 + cg * 4));
                *(ushort4*)(sA + nl * VROW + cg * 4) =
                    make_ushort4(f2b(v[0]), f2b(v[1]), f2b(v[2]), f2b(v[3]));
            }
        } else {
            const unsigned short* X = (const unsigned short*)Xv;
            int nl  = tid >> 2;
            int seg = tid & 3;
            int n   = n0 + nl;
            uint4 v = make_uint4(0, 0, 0, 0);
            if (n < nNodes)
                v = *(const uint4*)(X + (size_t)n * Kr + kc * 32 + seg * 8);
            *(uint4*)(sA + nl * VROW + seg * 8) = v;
        }
        __syncthreads();

        // ---- inner: 4 bfrags reused across FT afrags ----
        bf16x8 bfrag[4];
        #pragma unroll
        for (int nt = 0; nt < 4; ++nt)
            bfrag[nt] = *(const bf16x8*)(sA + (nt * 16 + l15) * VROW + q * 8);
        #pragma unroll
        for (int t = 0; t < FT; ++t) {
            bf16x8 afrag = *(const bf16x8*)(sV + ((tq + t) * 16 + l15) * VROW + q * 8);
            #pragma unroll
            for (int nt = 0; nt < 4; ++nt)
                acc[t][nt] = __builtin_amdgcn_mfma_f32_16x16x32_bf16(
                    afrag, bfrag[nt], acc[t][nt], 0, 0, 0);
        }
        __syncthreads();
    }

    // ---- epilogue ----
    float Fr = 1.f, Fi = 0.f, efr = 1.f, efi = 0.f;
    if constexpr (MIX) {
        float tr = trp[0], ti = tip[0];
        float er  = expf(ti);
        float tfr =  er * cosf(tr);
        float tfi = -er * sinf(tr);
        float eh  = expf(0.5f * ti);
        efr =  eh * cosf(0.5f * tr);
        efi = -eh * sinf(0.5f * tr);
        float omr = 1.f - efr, omi = -efi;
        Fr = tfr * omr - tfi * omi;
        Fi = tfr * omi + tfi * omr;
    }

    if constexpr (RED) {
        // fused abs + per-graph segmented sum; z never hits HBM.
        __shared__ __align__(16) float sRed[64 * 65];
        __shared__ int sBat[64];
        if (tid < 64) {
            int n = n0 + tid;
            sBat[tid] = (n < nNodes) ? batch[n] : -1;
        }
        #pragma unroll
        for (int nt = 0; nt < 4; ++nt) {
            int n = n0 + nt * 16 + l15;
            bool valid = n < nNodes;
            float dg = valid ? (float)degp[n] : 0.f;
            #pragma unroll
            for (int t = 0; t < FT; ++t) {
                int f0 = (tq + t) * 16 + q * 4;
                int j0 = f0 >> 1;
                float a0 = 0.f, a1 = 0.f;
                if (valid) {
                    float ar0 = acc[t][nt][0] + dg * br[j0];
                    float ai0 = acc[t][nt][1] + dg * bi[j0];
                    float ar1 = acc[t][nt][2] + dg * br[j0 + 1];
                    float ai1 = acc[t][nt][3] + dg * bi[j0 + 1];
                    float re0 = ar0 * Fr - ai0 * Fi, im0 = ar0 * Fi + ai0 * Fr;
                    float re1 = ar1 * Fr - ai1 * Fi, im1 = ar1 * Fi + ai1 * Fr;
                    ushort4 hu = *(const ushort4*)(Hin + (size_t)n * TWOJ + f0);
                    float hr0 = b2f(hu.x), hi0 = b2f(hu.y), hr1 = b2f(hu.z), hi1 = b2f(hu.w);
                    re0 += hr0 * efr - hi0 * efi;  im0 += hr0 * efi + hi0 * efr;
                    re1 += hr1 * efr - hi1 * efi;  im1 += hr1 * efi + hi1 * efr;
                    a0 = sqrtf(re0 * re0 + im0 * im0);
                    a1 = sqrtf(re1 * re1 + im1 * im1);
                }
                sRed[(nt * 16 + l15) * 65 + j0]     = a0;
                sRed[(nt * 16 + l15) * 65 + j0 + 1] = a1;
            }
        }
        __syncthreads();
        // 256 threads: feature j = tid&63, node quarter = tid>>6 (16 nodes)
        int j  = tid & 63;
        int q4 = tid >> 6;
        float accv = 0.f;
        int cg = sBat[q4 * 16];
        #pragma unroll
        for (int i = 0; i < 16; ++i) {
            int nl = q4 * 16 + i;
            int g = sBat[nl];
            if (g != cg) {
                if ((unsigned)cg < 64u) unsafeAtomicAdd(&sums[cg * 64 + j], accv);
                accv = 0.f;
                cg = g;
            }
            accv += sRed[nl * 65 + j];
        }
        if ((unsigned)cg < 64u) unsafeAtomicAdd(&sums[cg * 64 + j], accv);
        return;
    }

    #pragma unroll
    for (int nt = 0; nt < 4; ++nt) {
        int n = n0 + nt * 16 + l15;
        if (n >= nNodes) continue;
        float dg = 0.f;
        if constexpr (MIX) dg = (float)degp[n];
        #pragma unroll
        for (int t = 0; t < FT; ++t) {
            int f0 = (tq + t) * 16 + q * 4;
            int j0 = f0 >> 1;
            float re0, im0, re1, im1;
            if constexpr (MIX) {
                float ar0 = acc[t][nt][0] + dg * br[j0];
                float ai0 = acc[t][nt][1] + dg * bi[j0];
                float ar1 = acc[t][nt][2] + dg * br[j0 + 1];
                float ai1 = acc[t][nt][3] + dg * bi[j0 + 1];
                re0 = ar0 * Fr - ai0 * Fi;  im0 = ar0 * Fi + ai0 * Fr;
                re1 = ar1 * Fr - ai1 * Fi;  im1 = ar1 * Fi + ai1 * Fr;
                ushort4 hu = *(const ushort4*)(Hin + (size_t)n * TWOJ + f0);
                float hr0 = b2f(hu.x), hi0 = b2f(hu.y), hr1 = b2f(hu.z), hi1 = b2f(hu.w);
                re0 += hr0 * efr - hi0 * efi;  im0 += hr0 * efi + hi0 * efr;
                re1 += hr1 * efr - hi1 * efi;  im1 += hr1 * efi + hi1 * efr;
            } else {
                re0 = acc[t][nt][0] + br[j0];
                im0 = acc[t][nt][1] + bi[j0];
                re1 = acc[t][nt][2] + br[j0 + 1];
                im1 = acc[t][nt][3] + bi[j0 + 1];
                if constexpr (CRELU) {
                    re0 = fmaxf(re0, 0.f); im0 = fmaxf(im0, 0.f);
                    re1 = fmaxf(re1, 0.f); im1 = fmaxf(im1, 0.f);
                }
            }
            *(ushort4*)(Out + (size_t)n * TWOJ + f0) =
                make_ushort4(f2b(re0), f2b(im0), f2b(re1), f2b(im1));
            if constexpr (WF8) {
                int pk = 0;
                pk = __builtin_amdgcn_cvt_pk_fp8_f32(re0, im0, pk, false);
                pk = __builtin_amdgcn_cvt_pk_fp8_f32(re1, im1, pk, true);
                *(int*)(Of8 + (size_t)n * TWOJ + f0) = pk;
            }
        }
    }
}

// ---------------------------------------------------------------------------
// Fused GEMM2+GEMM3 (round 22 — proven: 84.8 us vs ~101 serial pair).
// ---------------------------------------------------------------------------
__global__ __launch_bounds__(256) void mfma_dual_kernel(
    const unsigned short* __restrict__ Xagg,
    const unsigned short* __restrict__ VM,
    const unsigned short* __restrict__ Vg2,
    const float* __restrict__ cr, const float* __restrict__ ci,
    const float* __restrict__ trp, const float* __restrict__ tip,
    const float* __restrict__ b1r, const float* __restrict__ b1i,
    const unsigned short* __restrict__ Hin,
    const int* __restrict__ degp,
    unsigned short* __restrict__ Out,
    unsigned char* __restrict__ Of8,
    int nNodes)
{
    constexpr int VROW = 40;
    __shared__ __align__(16) unsigned short sV[256 * VROW];
    __shared__ __align__(16) unsigned short sA[64 * VROW];
    __shared__ __align__(16) unsigned short x1b[8 * 64 * VROW];

    const int tid  = threadIdx.x;
    const int w    = tid >> 6;
    const int lane = tid & 63;
    const int l15  = lane & 15;
    const int q    = lane >> 4;
    const int n0   = blockIdx.x * 64;

    // ================= phase 1: x1 = MIX(aggA @ VM0, h0) =================
    {
        f32x4 acc[4][4];
        #pragma unroll
        for (int t = 0; t < 4; ++t)
            #pragma unroll
            for (int nt = 0; nt < 4; ++nt) acc[t][nt] = (f32x4){0.f, 0.f, 0.f, 0.f};

        for (int kc = 0; kc < 8; ++kc) {
            #pragma unroll
            for (int it = 0; it < 4; ++it) {
                int idx = it * 256 + tid;
                int row = idx >> 2;
                int seg = idx & 3;
                *(uint4*)(sV + row * VROW + seg * 8) =
                    *(const uint4*)(VM + (size_t)row * 256 + kc * 32 + seg * 8);
            }
            {
                int nl  = tid >> 2;
                int seg = tid & 3;
                int n   = n0 + nl;
                uint4 v = make_uint4(0, 0, 0, 0);
                if (n < nNodes)
                    v = *(const uint4*)(Xagg + (size_t)n * 256 + kc * 32 + seg * 8);
                *(uint4*)(sA + nl * VROW + seg * 8) = v;
            }
            __syncthreads();
            bf16x8 bfrag[4];
            #pragma unroll
            for (int nt = 0; nt < 4; ++nt)
                bfrag[nt] = *(const bf16x8*)(sA + (nt * 16 + l15) * VROW + q * 8);
            #pragma unroll
            for (int t = 0; t < 4; ++t) {
                bf16x8 afrag = *(const bf16x8*)(sV + ((w * 4 + t) * 16 + l15) * VROW + q * 8);
                #pragma unroll
                for (int nt = 0; nt < 4; ++nt)
                    acc[t][nt] = __builtin_amdgcn_mfma_f32_16x16x32_bf16(
                        afrag, bfrag[nt], acc[t][nt], 0, 0, 0);
            }
            __syncthreads();
        }

        float tr = trp[0], ti = tip[0];
        float er  = expf(ti);
        float tfr =  er * cosf(tr);
        float tfi = -er * sinf(tr);
        float eh  = expf(0.5f * ti);
        float efr =  eh * cosf(0.5f * tr);
        float efi = -eh * sinf(0.5f * tr);
        float omr = 1.f - efr, omi = -efi;
        float Fr = tfr * omr - tfi * omi;
        float Fi = tfr * omi + tfi * omr;

        #pragma unroll
        for (int nt = 0; nt < 4; ++nt) {
            int n = n0 + nt * 16 + l15;
            if (n >= nNodes) continue;
            float dg = (float)degp[n];
            #pragma unroll
            for (int t = 0; t < 4; ++t) {
                int f0 = (w * 4 + t) * 16 + q * 4;
                int j0 = f0 >> 1;
                float ar0 = acc[t][nt][0] + dg * cr[j0];
                float ai0 = acc[t][nt][1] + dg * ci[j0];
                float ar1 = acc[t][nt][2] + dg * cr[j0 + 1];
                float ai1 = acc[t][nt][3] + dg * ci[j0 + 1];
                float re0 = ar0 * Fr - ai0 * Fi, im0 = ar0 * Fi + ai0 * Fr;
                float re1 = ar1 * Fr - ai1 * Fi, im1 = ar1 * Fi + ai1 * Fr;
                ushort4 hu = *(const ushort4*)(Hin + (size_t)n * 256 + f0);
                float hr0 = b2f(hu.x), hi0 = b2f(hu.y), hr1 = b2f(hu.z), hi1 = b2f(hu.w);
                re0 += hr0 * efr - hi0 * efi;  im0 += hr0 * efi + hi0 * efr;
                re1 += hr1 * efr - hi1 * efi;  im1 += hr1 * efi + hi1 * efr;
                *(ushort4*)(x1b + ((f0 >> 5) * 64 + nt * 16 + l15) * VROW + (f0 & 31)) =
                    make_ushort4(f2b(re0), f2b(im0), f2b(re1), f2b(im1));
            }
        }
    }
    __syncthreads();

    // ================= phase 2: h1 = crelu(x1 @ V1 + b1) =================
    f32x4 acc2[2][4];
    #pragma unroll
    for (int t = 0; t < 2; ++t)
        #pragma unroll
        for (int nt = 0; nt < 4; ++nt) acc2[t][nt] = (f32x4){0.f, 0.f, 0.f, 0.f};

    for (int kc = 0; kc < 8; ++kc) {
        #pragma unroll
        for (int it = 0; it < 2; ++it) {
            int idx = it * 256 + tid;
            int row = idx >> 2;
            int seg = idx & 3;
            *(uint4*)(sV + row * VROW + seg * 8) =
                *(const uint4*)(Vg2 + (size_t)row * 256 + kc * 32 + seg * 8);
        }
        __syncthreads();
        bf16x8 bfrag[4];
        #pragma unroll
        for (int nt = 0; nt < 4; ++nt)
            bfrag[nt] = *(const bf16x8*)(x1b + ((size_t)(kc * 64 + nt * 16 + l15)) * VROW + q * 8);
        #pragma unroll
        for (int t = 0; t < 2; ++t) {
            bf16x8 afrag = *(const bf16x8*)(sV + ((w * 2 + t) * 16 + l15) * VROW + q * 8);
            #pragma unroll
            for (int nt = 0; nt < 4; ++nt)
                acc2[t][nt] = __builtin_amdgcn_mfma_f32_16x16x32_bf16(
                    afrag, bfrag[nt], acc2[t][nt], 0, 0, 0);
        }
        __syncthreads();
    }

    #pragma unroll
    for (int nt = 0; nt < 4; ++nt) {
        int n = n0 + nt * 16 + l15;
        if (n >= nNodes) continue;
        #pragma unroll
        for (int t = 0; t < 2; ++t) {
            int f0 = (w * 2 + t) * 16 + q * 4;
            int j0 = f0 >> 1;
            float re0 = fmaxf(acc2[t][nt][0] + b1r[j0], 0.f);
            float im0 = fmaxf(acc2[t][nt][1] + b1i[j0], 0.f);
            float re1 = fmaxf(acc2[t][nt][2] + b1r[j0 + 1], 0.f);
            float im1 = fmaxf(acc2[t][nt][3] + b1i[j0 + 1], 0.f);
            *(ushort4*)(Out + (size_t)n * 128 + f0) =
                make_ushort4(f2b(re0), f2b(im0), f2b(re1), f2b(im1));
            int pk = 0;
            pk = __builtin_amdgcn_cvt_pk_fp8_f32(re0, im0, pk, false);
            pk = __builtin_amdgcn_cvt_pk_fp8_f32(re1, im1, pk, true);
            *(int*)(Of8 + (size_t)n * 128 + f0) = pk;
        }
    }
}

// ---------------------------------------------------------------------------
// Gather-sum, fp8 payload IN, bf16 agg OUT; node-per-lane-group (round 15).
// ---------------------------------------------------------------------------
template<int ROWE>
__global__ __launch_bounds__(256) void gather_f8_kernel(
    const unsigned char* __restrict__ h8, unsigned short* __restrict__ agg,
    const int* __restrict__ deg, const int* __restrict__ csr, int N)
{
    constexpr int LPR = ROWE / 16;   // lanes per node: 16 or 8
    constexpr int NPW = 64 / LPR;    // nodes per wave: 4 or 8
    const int tid  = threadIdx.x;
    const int lane = tid & 63;
    const int wid  = (blockIdx.x * 256 + tid) >> 6;
    if (wid * NPW >= N) return;
    const int g    = lane / LPR;
    const int sub  = lane % LPR;
    const int nid  = wid * NPW + g;
    const bool nv  = nid < N;
    int dg = 0;
    if (nv) dg = min(deg[nid], 64);

    uint4 cq0 = make_uint4(0, 0, 0, 0), cq1 = make_uint4(0, 0, 0, 0);
    if (nv) {
        const uint4* cp = (const uint4*)csr + ((size_t)nid << 4);
        cq0 = cp[sub];
        if constexpr (LPR == 8) cq1 = cp[8 + sub];
    }

    int mx = dg;
    mx = max(mx, __shfl_xor(mx, 32, 64));
    mx = max(mx, __shfl_xor(mx, 16, 64));
    if constexpr (LPR == 8) mx = max(mx, __shfl_xor(mx, 8, 64));

    float a[16];
    #pragma unroll
    for (int k = 0; k < 16; ++k) a[k] = 0.f;

    const unsigned char* hp = h8 + sub * 16;
    const int gb = g * LPR;

    #define CVT16(uu)                                                          \
        {                                                                      \
            auto p0 = __builtin_amdgcn_cvt_pk_f32_fp8((uu).x, false);          \
            a[0] += p0[0];   a[1] += p0[1];                                    \
            auto p1 = __builtin_amdgcn_cvt_pk_f32_fp8((uu).x, true);           \
            a[2] += p1[0];   a[3] += p1[1];                                    \
            auto p2 = __builtin_amdgcn_cvt_pk_f32_fp8((uu).y, false);          \
            a[4] += p2[0];   a[5] += p2[1];                                    \
            auto p3 = __builtin_amdgcn_cvt_pk_f32_fp8((uu).y, true);           \
            a[6] += p3[0];   a[7] += p3[1];                                    \
            auto p4 = __builtin_amdgcn_cvt_pk_f32_fp8((uu).z, false);          \
            a[8] += p4[0];   a[9] += p4[1];                                    \
            auto p5 = __builtin_amdgcn_cvt_pk_f32_fp8((uu).z, true);           \
            a[10] += p5[0];  a[11] += p5[1];                                   \
            auto p6 = __builtin_amdgcn_cvt_pk_f32_fp8((uu).w, false);          \
            a[12] += p6[0];  a[13] += p6[1];                                   \
            auto p7 = __builtin_amdgcn_cvt_pk_f32_fp8((uu).w, true);           \
            a[14] += p7[0];  a[15] += p7[1];                                   \
        }

    for (int e = 0; e < mx; e += 8) {
        uint4 cq = cq0;
        if constexpr (LPR == 8) { if (e & 32) cq = cq1; }
        const int o0 = gb + ((e & (4 * LPR - 1)) >> 2);
        const int o1 = o0 + 1;
        int s0 = __shfl((int)cq.x, o0, 64);
        int s1 = __shfl((int)cq.y, o0, 64);
        int s2 = __shfl((int)cq.z, o0, 64);
        int s3 = __shfl((int)cq.w, o0, 64);
        int s4 = __shfl((int)cq.x, o1, 64);
        int s5 = __shfl((int)cq.y, o1, 64);
        int s6 = __shfl((int)cq.z, o1, 64);
        int s7 = __shfl((int)cq.w, o1, 64);
        uint4 u0 = make_uint4(0,0,0,0), u1 = make_uint4(0,0,0,0);
        uint4 u2 = make_uint4(0,0,0,0), u3 = make_uint4(0,0,0,0);
        uint4 u4 = make_uint4(0,0,0,0), u5 = make_uint4(0,0,0,0);
        uint4 u6 = make_uint4(0,0,0,0), u7 = make_uint4(0,0,0,0);
        if (e + 0 < dg) u0 = *(const uint4*)(hp + (size_t)(unsigned)s0 * ROWE);
        if (e + 1 < dg) u1 = *(const uint4*)(hp + (size_t)(unsigned)s1 * ROWE);
        if (e + 2 < dg) u2 = *(const uint4*)(hp + (size_t)(unsigned)s2 * ROWE);
        if (e + 3 < dg) u3 = *(const uint4*)(hp + (size_t)(unsigned)s3 * ROWE);
        if (e + 4 < dg) u4 = *(const uint4*)(hp + (size_t)(unsigned)s4 * ROWE);
        if (e + 5 < dg) u5 = *(const uint4*)(hp + (size_t)(unsigned)s5 * ROWE);
        if (e + 6 < dg) u6 = *(const uint4*)(hp + (size_t)(unsigned)s6 * ROWE);
        if (e + 7 < dg) u7 = *(const uint4*)(hp + (size_t)(unsigned)s7 * ROWE);
        CVT16(u0) CVT16(u1) CVT16(u2) CVT16(u3)
        CVT16(u4) CVT16(u5) CVT16(u6) CVT16(u7)
    }
    #undef CVT16

    if (nv) {
        unsigned short* op = agg + (size_t)nid * ROWE + sub * 16;
        *(ushort4*)(op)      = make_ushort4(f2b(a[0]),  f2b(a[1]),  f2b(a[2]),  f2b(a[3]));
        *(ushort4*)(op + 4)  = make_ushort4(f2b(a[4]),  f2b(a[5]),  f2b(a[6]),  f2b(a[7]));
        *(ushort4*)(op + 8)  = make_ushort4(f2b(a[8]),  f2b(a[9]),  f2b(a[10]), f2b(a[11]));
        *(ushort4*)(op + 12) = make_ushort4(f2b(a[12]), f2b(a[13]), f2b(a[14]), f2b(a[15]));
    }
}

// per-graph count via binary search (batch sorted) + mean + log_softmax
__global__ __launch_bounds__(64) void finalize_kernel(
    const float* __restrict__ sums, const int* __restrict__ batch,
    float* __restrict__ out, int N)
{
    int g = blockIdx.x, d = threadIdx.x;
    __shared__ int cnt_s;
    if (d == 0) {
        int lo = 0, hi = N;
        while (lo < hi) { int mid = (lo + hi) >> 1; if (batch[mid] < g) lo = mid + 1; else hi = mid; }
        int lo2 = lo, hi2 = N;
        while (lo2 < hi2) { int mid = (lo2 + hi2) >> 1; if (batch[mid] < g + 1) lo2 = mid + 1; else hi2 = mid; }
        cnt_s = lo2 - lo;
    }
    __syncthreads();
    float c = fmaxf((float)cnt_s, 1.0f);
    float m = sums[g * 64 + d] / c;
    float mx = m;
    #pragma unroll
    for (int o = 32; o > 0; o >>= 1) mx = fmaxf(mx, __shfl_xor(mx, o, 64));
    float e = expf(m - mx);
    float s = e;
    #pragma unroll
    for (int o = 32; o > 0; o >>= 1) s += __shfl_xor(s, o, 64);
    out[g * 64 + d] = m - mx - logf(s);
}

extern "C" void kernel_launch(void* const* d_in, const int* in_sizes, int n_in,
                              void* d_out, int out_size, void* d_ws, size_t ws_size,
                              hipStream_t stream)
{
    const float* x   = (const float*)d_in[0];
    const float* W0r = (const float*)d_in[1];
    const float* W0i = (const float*)d_in[2];
    const float* b0r = (const float*)d_in[3];
    const float* b0i = (const float*)d_in[4];
    const float* M0r = (const float*)d_in[5];
    const float* M0i = (const float*)d_in[6];
    const float* c0r = (const float*)d_in[7];
    const float* c0i = (const float*)d_in[8];
    const float* t0r = (const float*)d_in[9];
    const float* t0i = (const float*)d_in[10];
    const float* W1r = (const float*)d_in[11];
    const float* W1i = (const float*)d_in[12];
    const float* b1r = (const float*)d_in[13];
    const float* b1i = (const float*)d_in[14];
    const float* M1r = (const float*)d_in[15];
    const float* M1i = (const float*)d_in[16];
    const float* c1r = (const float*)d_in[17];
    const float* c1i = (const float*)d_in[18];
    const float* t1r = (const float*)d_in[19];
    const float* t1i = (const float*)d_in[20];
    const int* edge  = (const int*)d_in[21];
    const int* batch = (const int*)d_in[22];

    const int N = in_sizes[0] / 128;
    const int E = in_sizes[21] / 2;
    const int* src = edge;
    const int* dst = edge + E;

    // ---- workspace (~206 MB) ----
    unsigned short* h0   = (unsigned short*)d_ws;
    unsigned short* aggA = h0 + (size_t)N * 256;
    unsigned short* h1   = aggA + (size_t)N * 256;
    unsigned short* aggB = h1 + (size_t)N * 128;
    int*   deg  = (int*)(aggB + (size_t)N * 128);
    int*   csr  = deg + N;
    float* sums = (float*)(csr + (size_t)N * 64);
    unsigned short* V0  = (unsigned short*)(sums + 4096);  // [256,128]
    unsigned short* VM0 = V0  + 256 * 128;                 // [256,256]
    unsigned short* V1  = VM0 + 256 * 256;                 // [128,256]
    unsigned short* VM1 = V1  + 128 * 256;                 // [128,128]
    unsigned char* hf8 = (unsigned char*)(VM1 + 128 * 128);

    const int gemmGrid  = (N + 63) / 64;
    const int buildGrid = ((E + EDGE_CHUNK - 1) / EDGE_CHUNK) * 8;
    const int pbGrid    = 176 + buildGrid;
    const int g256Grid  = (N + 15) / 16;
    const int g128Grid  = (N + 31) / 32;

    // ---- zero deg/sums (DMA), then fused prep+build ----
    hipMemsetAsync(deg, 0, N * sizeof(int), stream);
    hipMemsetAsync(sums, 0, 4096 * sizeof(float), stream);
    prep_build_kernel<<<pbGrid, 256, 0, stream>>>(
        W0r, W0i, V0, M0r, M0i, VM0, W1r, W1i, V1, M1r, M1i, VM1,
        src, dst, deg, csr, E, N);

    // ---- layer 0 ----
    mfma_cgemm_kernel<128,256,0,true,false,true,false><<<gemmGrid, 256, 0, stream>>>(
        x, V0, b0r, b0i, nullptr, nullptr, nullptr, nullptr, h0, hf8,
        nullptr, nullptr, N);
    gather_f8_kernel<256><<<g256Grid, 256, 0, stream>>>(hf8, aggA, deg, csr, N);

    // ---- fused: x1 = MIX(aggA,h0) in LDS; h1 = crelu(x1 @ V1) + fp8 ----
    mfma_dual_kernel<<<gemmGrid, 256, 0, stream>>>(
        aggA, VM0, V1, c0r, c0i, t0r, t0i, b1r, b1i, h0, deg, h1, hf8, N);

    // ---- layer 1 tail: GEMM4 with fused abs+graph-sum (z never hits HBM) ----
    gather_f8_kernel<128><<<g128Grid, 256, 0, stream>>>(hf8, aggB, deg, csr, N);
    mfma_cgemm_kernel<128,128,1,false,true,false,true><<<gemmGrid, 256, 0, stream>>>(
        aggB, VM1, c1r, c1i, t1r, t1i, h1, deg, nullptr, nullptr,
        batch, sums, N);

    // ---- readout ----
    finalize_kernel<<<64, 64, 0, stream>>>(sums, batch, (float*)d_out, N);
}